// Round 3
// baseline (2200.170 us; speedup 1.0000x reference)
//
#include <hip/hip_runtime.h>
#include <hip/hip_bf16.h>
#include <cstdint>

#define N_NODES 50000
#define IN_DIM  512
#define HID     256
#define NEDGE   600000
#define TOPO    4
#define DEGMAX  96

typedef __attribute__((ext_vector_type(4))) float floatx4;
typedef _Float16 half4 __attribute__((ext_vector_type(4)));
typedef _Float16 half8 __attribute__((ext_vector_type(8)));

// ---------------- ordered-float <-> uint for atomicMax ---------------------------
static __device__ __forceinline__ unsigned f2ord(float f) {
  unsigned b = __float_as_uint(f);
  return (b & 0x80000000u) ? ~b : (b | 0x80000000u);
}
static __device__ __forceinline__ float ord2f(unsigned u) {
  unsigned b = (u & 0x80000000u) ? (u & 0x7fffffffu) : ~u;
  return __uint_as_float(b);
}

// ---------------- f32 -> f16 converters (run once) -------------------------------
__global__ void conv_f2h_kernel(const float* __restrict__ src, _Float16* __restrict__ dst, int n4) {
  int i = blockIdx.x * 256 + threadIdx.x;
  if (i < n4) {
    float4 v = ((const float4*)src)[i];
    half4 h;
    h[0] = (_Float16)v.x; h[1] = (_Float16)v.y; h[2] = (_Float16)v.z; h[3] = (_Float16)v.w;
    ((half4*)dst)[i] = h;
  }
}

// ctx = [style | stress] -> fp16 [N][512]
__global__ void conv_ctx_kernel(const float* __restrict__ style, const float* __restrict__ stress,
                                _Float16* __restrict__ dst) {
  int i = blockIdx.x * 256 + threadIdx.x;
  if (i >= N_NODES * 128) return;
  int n = i >> 7, c4 = i & 127;
  int c = c4 * 4;
  const float* s = (c < 256) ? (style + (size_t)n * 256 + c) : (stress + (size_t)n * 256 + (c - 256));
  float4 v = *(const float4*)s;
  half4 h;
  h[0] = (_Float16)v.x; h[1] = (_Float16)v.y; h[2] = (_Float16)v.z; h[3] = (_Float16)v.w;
  ((half4*)(dst + (size_t)n * 512))[c4] = h;
}

// ---- all 17 weight matrices -> fp16, transposed to Wt[n][kd], one dispatch ------
#define WT_FUS 0
#define WT_G0  131072
#define WT_G1  655360
#define WT_G2  917504
#define WT_AW  1179648
#define WT_TOT 1441792
__global__ void wconv_all_kernel(const float* __restrict__ fW1, const float* __restrict__ gW0,
                                 const float* __restrict__ gW1, const float* __restrict__ gW2,
                                 const float* __restrict__ aW, _Float16* __restrict__ wt) {
  int idx = blockIdx.x * 256 + threadIdx.x;
  if (idx >= WT_TOT) return;
  const float* src;
  int local, sh;
  if (idx < WT_G0) { src = fW1; sh = 9; local = idx; }
  else if (idx < WT_G1) { int r = idx - WT_G0; src = gW0 + (size_t)(r >> 17) * 131072; sh = 9; local = r & 131071; }
  else if (idx < WT_G2) { int r = idx - WT_G1; src = gW1 + (size_t)(r >> 16) * 65536; sh = 8; local = r & 65535; }
  else if (idx < WT_AW) { int r = idx - WT_G2; src = gW2 + (size_t)(r >> 16) * 65536; sh = 8; local = r & 65535; }
  else { int r = idx - WT_AW; src = aW + (size_t)(r >> 16) * 65536; sh = 8; local = r & 65535; }
  int n = local >> sh;
  int kd = local & ((1 << sh) - 1);
  wt[idx] = (_Float16)src[(size_t)kd * 256 + n];
}

// ---------------- GEMM: C[M,256] = A[M,KD] @ W[KD,256], fp16 MFMA ----------------
// Barrier-free: A and B fragments loaded directly global->reg (no LDS). Fragment
// addressing identical to the old LDS-staged layout:
//   a-frag[g] = A[r0+g*16+(lane&15)][it*32 + q*8 .. +8]
//   b-frag[t] = Wt[(wv*4+t)*16+(lane&15)][it*32 + q*8 .. +8]
// Full unroll folds it*64B into load offset immediates; depth-1 ping-pong
// prefetch + no barriers lets waves pipeline independently (the old per-K-iter
// __syncthreads drained every wave against the slowest global load at only
// ~3 waves/SIMD -> 14% MfmaUtil).
// bsh: batched launch decode — batch = blockIdx.x & ((1<<bsh)-1), tile = >> bsh
// (dispatch-adjacent batch blocks share the same A row-tile -> L2 reuse).
// mode 1 = tanh(x+bias). scale: optional per-row multiplier (GCN dinv).
template <int KD>
__global__ __launch_bounds__(256, 3) void gemm_f16_kernel(
    const _Float16* __restrict__ A, const _Float16* __restrict__ Wt0,
    const float* __restrict__ bias, _Float16* __restrict__ C0, int M, int mode,
    const float* __restrict__ scale, int wt_stride, int c_stride, int bsh) {
  constexpr int NIT = KD / 32;
  const int batch = blockIdx.x & ((1 << bsh) - 1);
  const int tile = blockIdx.x >> bsh;
  const _Float16* Wt = Wt0 + (size_t)batch * wt_stride;
  _Float16* C = C0 + (size_t)batch * c_stride;
  const int tid = threadIdx.x;
  const int lane = tid & 63;
  const int wv = tid >> 6;
  const int mr = lane & 15;
  const int q = (lane >> 4) & 3;
  const int r0 = tile * 64;

  const _Float16* pa[4];
#pragma unroll
  for (int g = 0; g < 4; ++g) {
    int row = r0 + g * 16 + mr;
    if (row > M - 1) row = M - 1;
    pa[g] = A + (size_t)row * KD + q * 8;
  }
  const _Float16* pb[4];
#pragma unroll
  for (int t = 0; t < 4; ++t)
    pb[t] = Wt + (size_t)((wv * 4 + t) * 16 + mr) * KD + q * 8;

  floatx4 acc[4][4];
#pragma unroll
  for (int g = 0; g < 4; ++g)
#pragma unroll
    for (int t = 0; t < 4; ++t) acc[g][t] = (floatx4){0.f, 0.f, 0.f, 0.f};

  half8 a0[4], b0[4], a1[4], b1[4];
#pragma unroll
  for (int g = 0; g < 4; ++g) a0[g] = *(const half8*)(pa[g]);
#pragma unroll
  for (int t = 0; t < 4; ++t) b0[t] = *(const half8*)(pb[t]);
  if (NIT > 1) {
#pragma unroll
    for (int g = 0; g < 4; ++g) a1[g] = *(const half8*)(pa[g] + 32);
#pragma unroll
    for (int t = 0; t < 4; ++t) b1[t] = *(const half8*)(pb[t] + 32);
  }

#pragma unroll
  for (int it = 0; it < NIT; it += 2) {
    // even iter: consume a0/b0
#pragma unroll
    for (int g = 0; g < 4; ++g)
#pragma unroll
      for (int t = 0; t < 4; ++t)
        acc[g][t] = __builtin_amdgcn_mfma_f32_16x16x32_f16(b0[t], a0[g], acc[g][t], 0, 0, 0);
    if (it + 2 < NIT) {  // refill a0/b0 for it+2 (offsets are compile-time imms)
#pragma unroll
      for (int g = 0; g < 4; ++g) a0[g] = *(const half8*)(pa[g] + (it + 2) * 32);
#pragma unroll
      for (int t = 0; t < 4; ++t) b0[t] = *(const half8*)(pb[t] + (it + 2) * 32);
    }
    // odd iter: consume a1/b1
    if (it + 1 < NIT) {
#pragma unroll
      for (int g = 0; g < 4; ++g)
#pragma unroll
        for (int t = 0; t < 4; ++t)
          acc[g][t] = __builtin_amdgcn_mfma_f32_16x16x32_f16(b1[t], a1[g], acc[g][t], 0, 0, 0);
      if (it + 3 < NIT) {
#pragma unroll
        for (int g = 0; g < 4; ++g) a1[g] = *(const half8*)(pa[g] + (it + 3) * 32);
#pragma unroll
        for (int t = 0; t < 4; ++t) b1[t] = *(const half8*)(pb[t] + (it + 3) * 32);
      }
    }
  }

  // Epilogue: lane holds rows r0+g*16+mr, cols c0..c0+3
  float sv[4];
#pragma unroll
  for (int g = 0; g < 4; ++g) {
    int row = r0 + g * 16 + mr;
    sv[g] = (scale && row < M) ? scale[row] : 1.f;
  }
#pragma unroll
  for (int t = 0; t < 4; ++t) {
    int c0 = (wv * 4 + t) * 16 + q * 4;
    float4 bv;
    if (bias) bv = *(const float4*)&bias[c0];
    else { bv.x = 0.f; bv.y = 0.f; bv.z = 0.f; bv.w = 0.f; }
#pragma unroll
    for (int g = 0; g < 4; ++g) {
      int row = r0 + g * 16 + mr;
      if (row < M) {
        half4 o;
#pragma unroll
        for (int r = 0; r < 4; ++r) {
          float v = acc[g][t][r] + (&bv.x)[r];
          if (mode == 1) v = tanhf(v);
          v *= sv[g];
          o[r] = (_Float16)v;
        }
        *(half4*)&C[(size_t)row * HID + c0] = o;
      }
    }
  }
}

// ---------------- CSR build (fixed-stride, no scan) ------------------------------
__global__ void zero_int_kernel(int* p, int n, unsigned* gmax) {
  int i = blockIdx.x * 256 + threadIdx.x;
  if (i < n) p[i] = 0;
  if (blockIdx.x == 0 && threadIdx.x < 8) gmax[threadIdx.x] = 0u;
}
__global__ void fill_kernel(const int* __restrict__ src, const int* __restrict__ dst,
                            int* __restrict__ cur, int* __restrict__ csr_src, int n) {
  int i = blockIdx.x * 256 + threadIdx.x;
  if (i < n) {
    int d = dst[i];
    int slot = atomicAdd(&cur[d], 1);
    if (slot < DEGMAX) csr_src[(size_t)d * DEGMAX + slot] = src[i];
  }
}
__global__ void dinv_kernel(const int* __restrict__ deg, float* __restrict__ dinv, int n) {
  int i = blockIdx.x * 256 + threadIdx.x;
  if (i < n) dinv[i] = rsqrtf((float)(deg[i] + 1));
}

// ---------------- GCN aggregation (pull), bias+ReLU fused ------------------------
// PRESCALED=1: hlin rows already carry dinv[row] (GEMM epilogue scale), neighbor
// update is pure load+add. PRESCALED=0 (hoisted GCN0): apply dinv[s] per neighbor.
// Software-pipelined: next index int4 + next feature rows issued before
// accumulating the current group.
template <int PRESCALED>
__global__ __launch_bounds__(256) void gcn_agg_kernel(
    const _Float16* __restrict__ hlin, const int* __restrict__ deg,
    const int* __restrict__ csr_src, const float* __restrict__ dinv,
    const float* __restrict__ bias, _Float16* __restrict__ out) {
  int w = (int)((blockIdx.x * blockDim.x + threadIdx.x) >> 6);
  int lane = threadIdx.x & 63;
  if (w >= N_NODES) return;
  float dv = dinv[w];
  half4 hv = ((const half4*)(hlin + (size_t)w * HID))[lane];
  float selfs = PRESCALED ? 1.f : dv;
  float A0 = (float)hv[0] * selfs, A1 = (float)hv[1] * selfs,
        A2 = (float)hv[2] * selfs, A3 = (float)hv[3] * selfs;
  float B0 = 0.f, B1 = 0.f, B2 = 0.f, B3 = 0.f;
  float C0 = 0.f, C1 = 0.f, C2 = 0.f, C3 = 0.f;
  float D0 = 0.f, D1 = 0.f, D2 = 0.f, D3 = 0.f;
  int dg = deg[w];
  if (dg > DEGMAX) dg = DEGMAX;
  const int* sp = csr_src + (size_t)w * DEGMAX;
  int s = 0;
  if (dg >= 4) {
    int4 iv = *(const int4*)sp;
    half4 p0 = ((const half4*)(hlin + (size_t)iv.x * HID))[lane];
    half4 p1 = ((const half4*)(hlin + (size_t)iv.y * HID))[lane];
    half4 p2 = ((const half4*)(hlin + (size_t)iv.z * HID))[lane];
    half4 p3 = ((const half4*)(hlin + (size_t)iv.w * HID))[lane];
    float e0 = 1.f, e1 = 1.f, e2 = 1.f, e3 = 1.f;
    if (!PRESCALED) { e0 = dinv[iv.x]; e1 = dinv[iv.y]; e2 = dinv[iv.z]; e3 = dinv[iv.w]; }
    for (s = 4; s + 4 <= dg; s += 4) {
      int4 nx = *(const int4*)(sp + s);
      half4 q0 = ((const half4*)(hlin + (size_t)nx.x * HID))[lane];
      half4 q1 = ((const half4*)(hlin + (size_t)nx.y * HID))[lane];
      half4 q2 = ((const half4*)(hlin + (size_t)nx.z * HID))[lane];
      half4 q3 = ((const half4*)(hlin + (size_t)nx.w * HID))[lane];
      float f0 = 1.f, f1 = 1.f, f2 = 1.f, f3 = 1.f;
      if (!PRESCALED) { f0 = dinv[nx.x]; f1 = dinv[nx.y]; f2 = dinv[nx.z]; f3 = dinv[nx.w]; }
      if (PRESCALED) {
        A0 += (float)p0[0]; A1 += (float)p0[1]; A2 += (float)p0[2]; A3 += (float)p0[3];
        B0 += (float)p1[0]; B1 += (float)p1[1]; B2 += (float)p1[2]; B3 += (float)p1[3];
        C0 += (float)p2[0]; C1 += (float)p2[1]; C2 += (float)p2[2]; C3 += (float)p2[3];
        D0 += (float)p3[0]; D1 += (float)p3[1]; D2 += (float)p3[2]; D3 += (float)p3[3];
      } else {
        A0 += (float)p0[0] * e0; A1 += (float)p0[1] * e0; A2 += (float)p0[2] * e0; A3 += (float)p0[3] * e0;
        B0 += (float)p1[0] * e1; B1 += (float)p1[1] * e1; B2 += (float)p1[2] * e1; B3 += (float)p1[3] * e1;
        C0 += (float)p2[0] * e2; C1 += (float)p2[1] * e2; C2 += (float)p2[2] * e2; C3 += (float)p2[3] * e2;
        D0 += (float)p3[0] * e3; D1 += (float)p3[1] * e3; D2 += (float)p3[2] * e3; D3 += (float)p3[3] * e3;
      }
      p0 = q0; p1 = q1; p2 = q2; p3 = q3;
      e0 = f0; e1 = f1; e2 = f2; e3 = f3;
    }
    if (PRESCALED) {
      A0 += (float)p0[0]; A1 += (float)p0[1]; A2 += (float)p0[2]; A3 += (float)p0[3];
      B0 += (float)p1[0]; B1 += (float)p1[1]; B2 += (float)p1[2]; B3 += (float)p1[3];
      C0 += (float)p2[0]; C1 += (float)p2[1]; C2 += (float)p2[2]; C3 += (float)p2[3];
      D0 += (float)p3[0]; D1 += (float)p3[1]; D2 += (float)p3[2]; D3 += (float)p3[3];
    } else {
      A0 += (float)p0[0] * e0; A1 += (float)p0[1] * e0; A2 += (float)p0[2] * e0; A3 += (float)p0[3] * e0;
      B0 += (float)p1[0] * e1; B1 += (float)p1[1] * e1; B2 += (float)p1[2] * e1; B3 += (float)p1[3] * e1;
      C0 += (float)p2[0] * e2; C1 += (float)p2[1] * e2; C2 += (float)p2[2] * e2; C3 += (float)p2[3] * e2;
      D0 += (float)p3[0] * e3; D1 += (float)p3[1] * e3; D2 += (float)p3[2] * e3; D3 += (float)p3[3] * e3;
    }
  }
  for (; s < dg; ++s) {
    int sc = sp[s];
    float nr = PRESCALED ? 1.f : dinv[sc];
    half4 v = ((const half4*)(hlin + (size_t)sc * HID))[lane];
    A0 += (float)v[0] * nr; A1 += (float)v[1] * nr;
    A2 += (float)v[2] * nr; A3 += (float)v[3] * nr;
  }
  float4 b = ((const float4*)bias)[lane];
  half4 r;
  r[0] = (_Float16)fmaxf((A0 + B0 + C0 + D0) * dv + b.x, 0.f);
  r[1] = (_Float16)fmaxf((A1 + B1 + C1 + D1) * dv + b.y, 0.f);
  r[2] = (_Float16)fmaxf((A2 + B2 + C2 + D2) * dv + b.z, 0.f);
  r[3] = (_Float16)fmaxf((A3 + B3 + C3 + D3) * dv + b.w, 0.f);
  ((half4*)(out + (size_t)w * HID))[lane] = r;
}

// ---------------- GAT: per-node attention coefficients ---------------------------
__global__ __launch_bounds__(256) void gat_prep_kernel(
    const _Float16* __restrict__ hlin, const float* __restrict__ a_src,
    const float* __restrict__ a_dst, float* __restrict__ asad) {
  int w = (int)((blockIdx.x * blockDim.x + threadIdx.x) >> 6);
  int lane = threadIdx.x & 63;
  if (w >= N_NODES) return;
  half4 h = ((const half4*)(hlin + (size_t)w * HID))[lane];
  float4 s4 = ((const float4*)a_src)[lane];
  float4 d4 = ((const float4*)a_dst)[lane];
  float hx = h[0], hy = h[1], hz = h[2], hw = h[3];
  float ps = hx * s4.x + hy * s4.y + hz * s4.z + hw * s4.w;
  float pd = hx * d4.x + hy * d4.y + hz * d4.z + hw * d4.w;
  for (int o = 1; o < 8; o <<= 1) { ps += __shfl_xor(ps, o, 64); pd += __shfl_xor(pd, o, 64); }
  if ((lane & 7) == 0) {
    int hh = lane >> 3;
    asad[(size_t)w * 16 + hh] = ps;
    asad[(size_t)w * 16 + 8 + hh] = pd;
  }
}

// ---------------- per-head global max of a_src projections -----------------------
__global__ __launch_bounds__(256) void gmax_kernel(const float* __restrict__ asad,
                                                   unsigned* __restrict__ gmax) {
  int t = threadIdx.x;
  int h = t & 7;
  float m = -1e30f;
  for (int n = blockIdx.x * 32 + (t >> 3); n < N_NODES; n += gridDim.x * 32)
    m = fmaxf(m, asad[(size_t)n * 16 + h]);
  m = fmaxf(m, __shfl_xor(m, 8, 64));
  m = fmaxf(m, __shfl_xor(m, 16, 64));
  m = fmaxf(m, __shfl_xor(m, 32, 64));
  if ((t & 63) < 8) atomicMax(&gmax[h], f2ord(m));
}

static __device__ __forceinline__ float lrelu(float e) {
  return e > 0.f ? e : 0.2f * e;
}

// ---------------- GAT aggregation + LayerNorm + weighted accumulate --------------
__global__ __launch_bounds__(256) void gat_agg_kernel(
    const _Float16* __restrict__ hlin, const int* __restrict__ deg,
    const int* __restrict__ csr_src, const float* __restrict__ asad,
    const unsigned* __restrict__ gmax, const float* __restrict__ bias,
    const float* __restrict__ lng, const float* __restrict__ lnb,
    const float* __restrict__ wsel, int kk, float* __restrict__ dout) {
  int w = (int)((blockIdx.x * blockDim.x + threadIdx.x) >> 6);
  int lane = threadIdx.x & 63;
  if (w >= N_NODES) return;
  int head = lane >> 3;
  int e7 = lane & 7;
  int gsel = lane >> 4;
  float ad_d = asad[(size_t)w * 16 + 8 + head];
  float m = lrelu(ord2f(gmax[head]) + ad_d);
  float e_self = lrelu(asad[(size_t)w * 16 + head] + ad_d);
  float ad_e = __shfl(ad_d, e7 << 3, 64);
  float m_e = __shfl(m, e7 << 3, 64);
  int dg = deg[w];
  if (dg > DEGMAX) dg = DEGMAX;
  const int* sp = csr_src + (size_t)w * DEGMAX;
  float lA = __expf(e_self - m), lB = 0.f, lC = 0.f, lD = 0.f;
  half4 hv = ((const half4*)(hlin + (size_t)w * HID))[lane];
  float A0 = (float)hv[0] * lA, A1 = (float)hv[1] * lA,
        A2 = (float)hv[2] * lA, A3 = (float)hv[3] * lA;
  float B0 = 0.f, B1 = 0.f, B2 = 0.f, B3 = 0.f;
  float C0 = 0.f, C1 = 0.f, C2 = 0.f, C3 = 0.f;
  float D0 = 0.f, D1 = 0.f, D2 = 0.f, D3 = 0.f;
  int ng = (dg + 3) >> 2;
  int4 iv;
  if (ng) iv = *(const int4*)sp;
  for (int gi = 0; gi < ng; ++gi) {
    int s4 = gi << 2;
    int rem = dg - s4;
    bool tail = rem < 4;
    if (tail) {
      if (rem < 2) iv.y = iv.x;
      if (rem < 3) iv.z = iv.x;
      iv.w = iv.x;
    }
    int nsel = gsel == 0 ? iv.x : gsel == 1 ? iv.y : gsel == 2 ? iv.z : iv.w;
    float av = asad[(size_t)nsel * 16 + e7];
    half4 v0 = ((const half4*)(hlin + (size_t)iv.x * HID))[lane];
    half4 v1 = ((const half4*)(hlin + (size_t)iv.y * HID))[lane];
    half4 v2 = ((const half4*)(hlin + (size_t)iv.z * HID))[lane];
    half4 v3 = ((const half4*)(hlin + (size_t)iv.w * HID))[lane];
    int4 nx = iv;
    if (gi + 1 < ng) nx = *(const int4*)(sp + s4 + 4);
    float ve = __expf(lrelu(av + ad_e) - m_e);
    float w0 = __shfl(ve, head, 64);
    float w1 = __shfl(ve, 16 + head, 64);
    float w2 = __shfl(ve, 32 + head, 64);
    float w3 = __shfl(ve, 48 + head, 64);
    if (tail) {
      if (rem < 2) w1 = 0.f;
      if (rem < 3) w2 = 0.f;
      w3 = 0.f;
    }
    lA += w0; lB += w1; lC += w2; lD += w3;
    A0 += (float)v0[0] * w0; A1 += (float)v0[1] * w0; A2 += (float)v0[2] * w0; A3 += (float)v0[3] * w0;
    B0 += (float)v1[0] * w1; B1 += (float)v1[1] * w1; B2 += (float)v1[2] * w1; B3 += (float)v1[3] * w1;
    C0 += (float)v2[0] * w2; C1 += (float)v2[1] * w2; C2 += (float)v2[2] * w2; C3 += (float)v2[3] * w2;
    D0 += (float)v3[0] * w3; D1 += (float)v3[1] * w3; D2 += (float)v3[2] * w3; D3 += (float)v3[3] * w3;
    iv = nx;
  }
  float inv = 1.f / (lA + lB + lC + lD);
  float4 b = ((const float4*)bias)[lane];
  float vx = (A0 + B0 + C0 + D0) * inv + b.x;
  float vy = (A1 + B1 + C1 + D1) * inv + b.y;
  float vz = (A2 + B2 + C2 + D2) * inv + b.z;
  float vw = (A3 + B3 + C3 + D3) * inv + b.w;
  float ssum = vx + vy + vz + vw;
  for (int o = 1; o < 64; o <<= 1) ssum += __shfl_xor(ssum, o, 64);
  float mu = ssum * (1.f / HID);
  float dx = vx - mu, dy = vy - mu, dz = vz - mu, dw = vw - mu;
  float qq = dx * dx + dy * dy + dz * dz + dw * dw;
  for (int o = 1; o < 64; o <<= 1) qq += __shfl_xor(qq, o, 64);
  float rs = rsqrtf(qq * (1.f / HID) + 1e-5f);
  float4 g4 = ((const float4*)lng)[lane];
  float4 b4 = ((const float4*)lnb)[lane];
  float wk = wsel[(size_t)w * 4 + kk];
  float4 r;
  r.x = (dx * rs * g4.x + b4.x) * wk;
  r.y = (dy * rs * g4.y + b4.y) * wk;
  r.z = (dz * rs * g4.z + b4.z) * wk;
  r.w = (dw * rs * g4.w + b4.w) * wk;
  float4* dp = (float4*)(dout + (size_t)w * HID) + lane;
  if (kk == 0) {
    *dp = r;
  } else {
    float4 old = *dp;
    old.x += r.x; old.y += r.y; old.z += r.z; old.w += r.w;
    *dp = old;
  }
}

// ---------------- fusion weights: logits = t @ W2 + b2, softmax(K=4) --------------
__global__ __launch_bounds__(256) void fusw_kernel(
    const _Float16* __restrict__ t, const float* __restrict__ W2,
    const float* __restrict__ b2, float* __restrict__ wout) {
  int w = (int)((blockIdx.x * blockDim.x + threadIdx.x) >> 6);
  int lane = threadIdx.x & 63;
  if (w >= N_NODES) return;
  half4 t4h = ((const half4*)(t + (size_t)w * HID))[lane];
  float tx = t4h[0], ty = t4h[1], tz = t4h[2], tw = t4h[3];
  int c = lane * 4;
  float4 w0 = ((const float4*)W2)[c + 0];
  float4 w1 = ((const float4*)W2)[c + 1];
  float4 w2 = ((const float4*)W2)[c + 2];
  float4 w3 = ((const float4*)W2)[c + 3];
  float p0 = tx * w0.x + ty * w1.x + tz * w2.x + tw * w3.x;
  float p1 = tx * w0.y + ty * w1.y + tz * w2.y + tw * w3.y;
  float p2 = tx * w0.z + ty * w1.z + tz * w2.z + tw * w3.z;
  float p3 = tx * w0.w + ty * w1.w + tz * w2.w + tw * w3.w;
  for (int o = 1; o < 64; o <<= 1) {
    p0 += __shfl_xor(p0, o, 64); p1 += __shfl_xor(p1, o, 64);
    p2 += __shfl_xor(p2, o, 64); p3 += __shfl_xor(p3, o, 64);
  }
  if (lane == 0) {
    p0 += b2[0]; p1 += b2[1]; p2 += b2[2]; p3 += b2[3];
    float mx = fmaxf(fmaxf(p0, p1), fmaxf(p2, p3));
    float e0 = __expf(p0 - mx), e1 = __expf(p1 - mx), e2 = __expf(p2 - mx), e3 = __expf(p3 - mx);
    float inv = 1.f / (e0 + e1 + e2 + e3);
    float4 r; r.x = e0 * inv; r.y = e1 * inv; r.z = e2 * inv; r.w = e3 * inv;
    ((float4*)wout)[w] = r;
  }
}

extern "C" void kernel_launch(void* const* d_in, const int* in_sizes, int n_in,
                              void* d_out, int out_size, void* d_ws, size_t ws_size,
                              hipStream_t stream) {
  const float* x      = (const float*)d_in[0];
  const float* style  = (const float*)d_in[1];
  const float* stress = (const float*)d_in[2];
  const int* edges[4] = {(const int*)d_in[3], (const int*)d_in[4],
                         (const int*)d_in[5], (const int*)d_in[6]};
  const float* gW0 = (const float*)d_in[7];
  const float* gb0 = (const float*)d_in[8];
  const float* gW1 = (const float*)d_in[9];
  const float* gb1 = (const float*)d_in[10];
  const float* gW2 = (const float*)d_in[11];
  const float* gb2 = (const float*)d_in[12];
  const float* aW  = (const float*)d_in[13];
  const float* aas = (const float*)d_in[14];
  const float* aad = (const float*)d_in[15];
  const float* ab  = (const float*)d_in[16];
  const float* lg  = (const float*)d_in[17];
  const float* lb  = (const float*)d_in[18];
  const float* fW1 = (const float*)d_in[19];
  const float* fb1 = (const float*)d_in[20];
  const float* fW2 = (const float*)d_in[21];
  const float* fb2 = (const float*)d_in[22];
  float* out = (float*)d_out;
  (void)in_sizes; (void)n_in; (void)out_size;

  char* wsp = (char*)d_ws;
  size_t off = 0;
  auto alloc = [&](size_t bytes) -> void* {
    void* p = wsp + off;
    off += (bytes + 255) & ~(size_t)255;
    return p;
  };
  auto al = [](size_t b) { return (b + 255) & ~(size_t)255; };

  const size_t sz_hact = (size_t)N_NODES * HID * 2;
  const size_t sz_xh   = (size_t)N_NODES * IN_DIM * 2;
  const size_t sz_csr  = (size_t)N_NODES * DEGMAX * 4;
  const size_t sz_hlin0 = (size_t)4 * N_NODES * HID * 2;  // 102.4 MB

  const size_t fixed = al(sz_hact) * 2 + al(sz_xh) + al((size_t)WT_TOT * 2) +
                       al((size_t)N_NODES * 16) + al((size_t)N_NODES * 4) * 2 +
                       al((size_t)N_NODES * 64) + al(256);
  const size_t need_hoist = fixed + al(sz_csr) + al(sz_hlin0);
  const bool hoist = ws_size >= need_hoist;

  _Float16* h_act = (_Float16*)alloc(sz_hact);
  _Float16* h_lin = (_Float16*)alloc(sz_hact);
  _Float16* x_h   = (_Float16*)alloc(sz_xh);
  _Float16* wtall = (_Float16*)alloc((size_t)WT_TOT * 2);
  float* wsel = (float*)alloc((size_t)N_NODES * 16);
  float* dinv = (float*)alloc((size_t)N_NODES * 4);
  int* cur = (int*)alloc((size_t)N_NODES * 4);
  float* asad = (float*)alloc((size_t)N_NODES * 64);
  unsigned* gmax = (unsigned*)alloc(256);
  _Float16* ctx_h;
  int* csr_src;
  _Float16* h_lin0 = nullptr;
  if (hoist) {
    csr_src = (int*)alloc(sz_csr);
    char* region = (char*)alloc(sz_hlin0);  // ctx_h lives here until fusion GEMM done
    ctx_h = (_Float16*)region;
    h_lin0 = (_Float16*)region;
  } else {
    char* shared_region = (char*)alloc(sz_xh);  // 51.2 MB: ctx then csr
    ctx_h = (_Float16*)shared_region;
    csr_src = (int*)shared_region;
  }

  dim3 blk(256);
  const int nodeWaveBlocks = N_NODES / 4;
  const int nBlocksN = (N_NODES + 255) / 256;
  const int nBlocksE = (NEDGE + 255) / 256;
  const int gemmBlocks = (N_NODES + 63) / 64;  // 782

  // ---- one-time conversions ----
  conv_f2h_kernel<<<(N_NODES * IN_DIM / 4 + 255) / 256, blk, 0, stream>>>(x, x_h, N_NODES * IN_DIM / 4);
  conv_ctx_kernel<<<(N_NODES * 128 + 255) / 256, blk, 0, stream>>>(style, stress, ctx_h);
  wconv_all_kernel<<<(WT_TOT + 255) / 256, blk, 0, stream>>>(fW1, gW0, gW1, gW2, aW, wtall);

  // ---- fusion gate ----
  gemm_f16_kernel<512><<<gemmBlocks, blk, 0, stream>>>(ctx_h, wtall + WT_FUS, fb1, h_lin,
                                                       N_NODES, 1, nullptr, 0, 0, 0);
  fusw_kernel<<<nodeWaveBlocks, blk, 0, stream>>>(h_lin, fW2, fb2, wsel);

  // ---- hoisted GCN0 linear: x @ W0_k for all 4 topologies, one 1-D dispatch ----
  // batch = blockIdx.x & 3 so the 4 blocks sharing an A row-tile are adjacent.
  if (hoist) {
    gemm_f16_kernel<512><<<gemmBlocks * 4, blk, 0, stream>>>(
        x_h, wtall + WT_G0, nullptr, h_lin0, N_NODES, 0, nullptr,
        131072, N_NODES * HID, 2);
  }

  for (int k = 0; k < TOPO; ++k) {
    const int* srcp = edges[k];
    const int* dstp = edges[k] + NEDGE;
    zero_int_kernel<<<nBlocksN, blk, 0, stream>>>(cur, N_NODES, gmax);
    fill_kernel<<<nBlocksE, blk, 0, stream>>>(srcp, dstp, cur, csr_src, NEDGE);
    dinv_kernel<<<nBlocksN, blk, 0, stream>>>(cur, dinv, N_NODES);

    // GCN0 (512 -> 256)
    if (hoist) {
      gcn_agg_kernel<0><<<nodeWaveBlocks, blk, 0, stream>>>(
          h_lin0 + (size_t)k * N_NODES * HID, cur, csr_src, dinv,
          gb0 + (size_t)k * HID, h_act);
    } else {
      gemm_f16_kernel<512><<<gemmBlocks, blk, 0, stream>>>(
          x_h, wtall + WT_G0 + (size_t)k * 131072, nullptr, h_lin, N_NODES, 0, dinv, 0, 0, 0);
      gcn_agg_kernel<1><<<nodeWaveBlocks, blk, 0, stream>>>(h_lin, cur, csr_src, dinv,
                                                            gb0 + (size_t)k * HID, h_act);
    }
    // GCN1
    gemm_f16_kernel<256><<<gemmBlocks, blk, 0, stream>>>(
        h_act, wtall + WT_G1 + (size_t)k * 65536, nullptr, h_lin, N_NODES, 0, dinv, 0, 0, 0);
    gcn_agg_kernel<1><<<nodeWaveBlocks, blk, 0, stream>>>(h_lin, cur, csr_src, dinv,
                                                          gb1 + (size_t)k * HID, h_act);
    // GCN2
    gemm_f16_kernel<256><<<gemmBlocks, blk, 0, stream>>>(
        h_act, wtall + WT_G2 + (size_t)k * 65536, nullptr, h_lin, N_NODES, 0, dinv, 0, 0, 0);
    gcn_agg_kernel<1><<<nodeWaveBlocks, blk, 0, stream>>>(h_lin, cur, csr_src, dinv,
                                                          gb2 + (size_t)k * HID, h_act);
    // GAT (unscaled linear output)
    gemm_f16_kernel<256><<<gemmBlocks, blk, 0, stream>>>(
        h_act, wtall + WT_AW + (size_t)k * 65536, nullptr, h_lin, N_NODES, 0, nullptr, 0, 0, 0);
    gat_prep_kernel<<<nodeWaveBlocks, blk, 0, stream>>>(h_lin, aas + (size_t)k * HID,
                                                        aad + (size_t)k * HID, asad);
    gmax_kernel<<<64, blk, 0, stream>>>(asad, gmax);
    gat_agg_kernel<<<nodeWaveBlocks, blk, 0, stream>>>(h_lin, cur, csr_src, asad, gmax,
                                                       ab + (size_t)k * HID,
                                                       lg + (size_t)k * HID,
                                                       lb + (size_t)k * HID,
                                                       wsel, k, out);
  }
}

// Round 4
// 1825.919 us; speedup vs baseline: 1.2050x; 1.2050x over previous
//
#include <hip/hip_runtime.h>
#include <hip/hip_bf16.h>
#include <cstdint>

#define N_NODES 50000
#define IN_DIM  512
#define HID     256
#define NEDGE   600000
#define TOPO    4
#define DEGMAX  96

typedef __attribute__((ext_vector_type(4))) float floatx4;
typedef _Float16 half4 __attribute__((ext_vector_type(4)));
typedef _Float16 half8 __attribute__((ext_vector_type(8)));

// ---------------- ordered-float <-> uint for atomicMax ---------------------------
static __device__ __forceinline__ unsigned f2ord(float f) {
  unsigned b = __float_as_uint(f);
  return (b & 0x80000000u) ? ~b : (b | 0x80000000u);
}
static __device__ __forceinline__ float ord2f(unsigned u) {
  unsigned b = (u & 0x80000000u) ? (u & 0x7fffffffu) : ~u;
  return __uint_as_float(b);
}

// ---------------- f32 -> f16 converters (run once) -------------------------------
__global__ void conv_f2h_kernel(const float* __restrict__ src, _Float16* __restrict__ dst, int n4) {
  int i = blockIdx.x * 256 + threadIdx.x;
  if (i < n4) {
    float4 v = ((const float4*)src)[i];
    half4 h;
    h[0] = (_Float16)v.x; h[1] = (_Float16)v.y; h[2] = (_Float16)v.z; h[3] = (_Float16)v.w;
    ((half4*)dst)[i] = h;
  }
}

// ctx = [style | stress] -> fp16 [N][512]
__global__ void conv_ctx_kernel(const float* __restrict__ style, const float* __restrict__ stress,
                                _Float16* __restrict__ dst) {
  int i = blockIdx.x * 256 + threadIdx.x;
  if (i >= N_NODES * 128) return;
  int n = i >> 7, c4 = i & 127;
  int c = c4 * 4;
  const float* s = (c < 256) ? (style + (size_t)n * 256 + c) : (stress + (size_t)n * 256 + (c - 256));
  float4 v = *(const float4*)s;
  half4 h;
  h[0] = (_Float16)v.x; h[1] = (_Float16)v.y; h[2] = (_Float16)v.z; h[3] = (_Float16)v.w;
  ((half4*)(dst + (size_t)n * 512))[c4] = h;
}

// ---- all 17 weight matrices -> fp16, transposed to Wt[n][kd], one dispatch ------
#define WT_FUS 0
#define WT_G0  131072
#define WT_G1  655360
#define WT_G2  917504
#define WT_AW  1179648
#define WT_TOT 1441792
__global__ void wconv_all_kernel(const float* __restrict__ fW1, const float* __restrict__ gW0,
                                 const float* __restrict__ gW1, const float* __restrict__ gW2,
                                 const float* __restrict__ aW, _Float16* __restrict__ wt) {
  int idx = blockIdx.x * 256 + threadIdx.x;
  if (idx >= WT_TOT) return;
  const float* src;
  int local, sh;
  if (idx < WT_G0) { src = fW1; sh = 9; local = idx; }
  else if (idx < WT_G1) { int r = idx - WT_G0; src = gW0 + (size_t)(r >> 17) * 131072; sh = 9; local = r & 131071; }
  else if (idx < WT_G2) { int r = idx - WT_G1; src = gW1 + (size_t)(r >> 16) * 65536; sh = 8; local = r & 65535; }
  else if (idx < WT_AW) { int r = idx - WT_G2; src = gW2 + (size_t)(r >> 16) * 65536; sh = 8; local = r & 65535; }
  else { int r = idx - WT_AW; src = aW + (size_t)(r >> 16) * 65536; sh = 8; local = r & 65535; }
  int n = local >> sh;
  int kd = local & ((1 << sh) - 1);
  wt[idx] = (_Float16)src[(size_t)kd * 256 + n];
}

// ---------------- GEMM: C[M,256] = A[M,KD] @ W[KD,256], fp16 MFMA ----------------
// Tile 64 rows x 256 cols per block (256 threads, 4 waves; wave wv owns cols
// [wv*64, wv*64+64)). A staged in LDS in fragment order (conflict-free b128 both
// ways); B frags direct global->reg with 1-iter prefetch; LDS double-buffered,
// one barrier per K-iter (R3 lesson: LDS A-staging = 4x load-path compression
// across waves; barrier-free global->reg regressed 152->246 us).
// b-frag t covers weight cols wcol(t,mr) = wv*64+(t>>1)*32+(mr>>2)*8+(mr&3)+(t&1)*4
// so lane (mr,q) holds 8 CONSECUTIVE output cols per t-pair -> half8 stores, each
// wave-store covers 16 full 64B lines (kills the measured 1.9x write
// amplification of the old scattered half4 epilogue).
// blockIdx.y selects a weight/output pair (batched GCN0). mode 1 = tanh(x+bias).
// scale: optional per-row multiplier (GCN dinv pre-scaling).
template <int KD>
__global__ __launch_bounds__(256, 3) void gemm_f16_kernel(
    const _Float16* __restrict__ A, const _Float16* __restrict__ Wt0,
    const float* __restrict__ bias, _Float16* __restrict__ C0, int M, int mode,
    const float* __restrict__ scale, int wt_stride, int c_stride) {
  constexpr int NIT = KD / 32;
  const _Float16* Wt = Wt0 + (size_t)blockIdx.y * wt_stride;
  _Float16* C = C0 + (size_t)blockIdx.y * c_stride;
  __shared__ __align__(16) _Float16 As[2][2048];  // 4 frags x 64 lanes x 8 halves
  const int tid = threadIdx.x;
  const int lane = tid & 63;
  const int wv = tid >> 6;
  const int mr = lane & 15;
  const int q = (lane >> 4) & 3;
  const int r0 = blockIdx.x * 64;

  int arow = r0 + ((tid >> 6) * 16) + (tid & 15);
  if (arow > M - 1) arow = M - 1;
  const _Float16* pa = A + (size_t)arow * KD + ((tid >> 4) & 3) * 8;
  const _Float16* pb[4];
#pragma unroll
  for (int t = 0; t < 4; ++t) {
    int wcol = wv * 64 + (t >> 1) * 32 + ((mr >> 2) * 8) + (mr & 3) + (t & 1) * 4;
    pb[t] = Wt + (size_t)wcol * KD + q * 8;
  }

  floatx4 acc[4][4];
#pragma unroll
  for (int g = 0; g < 4; ++g)
#pragma unroll
    for (int t = 0; t < 4; ++t) acc[g][t] = (floatx4){0.f, 0.f, 0.f, 0.f};

  half8 a0, a1, b0[4], b1[4];
  a0 = *(const half8*)pa; pa += 32;
#pragma unroll
  for (int t = 0; t < 4; ++t) { b0[t] = *(const half8*)pb[t]; pb[t] += 32; }
  *(half8*)&As[0][(unsigned)tid * 8] = a0;
  if (NIT > 1) { a1 = *(const half8*)pa; pa += 32; }
  __syncthreads();

#pragma unroll 1
  for (int it = 0; it < NIT; it += 2) {
    // ---- even half: compute from As[0] with b0 ----
    if (it + 1 < NIT) {
      *(half8*)&As[1][(unsigned)tid * 8] = a1;
#pragma unroll
      for (int t = 0; t < 4; ++t) { b1[t] = *(const half8*)pb[t]; pb[t] += 32; }
      if (it + 2 < NIT) { a0 = *(const half8*)pa; pa += 32; }
    }
    {
      half8 af[4];
#pragma unroll
      for (int g = 0; g < 4; ++g) af[g] = *(const half8*)&As[0][(g * 64 + lane) * 8];
#pragma unroll
      for (int g = 0; g < 4; ++g)
#pragma unroll
        for (int t = 0; t < 4; ++t)
          acc[g][t] = __builtin_amdgcn_mfma_f32_16x16x32_f16(b0[t], af[g], acc[g][t], 0, 0, 0);
    }
    if (it + 1 < NIT) {
      __syncthreads();
      // ---- odd half: compute from As[1] with b1 ----
      if (it + 2 < NIT) {
        *(half8*)&As[0][(unsigned)tid * 8] = a0;
#pragma unroll
        for (int t = 0; t < 4; ++t) { b0[t] = *(const half8*)pb[t]; pb[t] += 32; }
        if (it + 3 < NIT) { a1 = *(const half8*)pa; pa += 32; }
      }
      half8 af[4];
#pragma unroll
      for (int g = 0; g < 4; ++g) af[g] = *(const half8*)&As[1][(g * 64 + lane) * 8];
#pragma unroll
      for (int g = 0; g < 4; ++g)
#pragma unroll
        for (int t = 0; t < 4; ++t)
          acc[g][t] = __builtin_amdgcn_mfma_f32_16x16x32_f16(b1[t], af[g], acc[g][t], 0, 0, 0);
      if (it + 2 < NIT) __syncthreads();
    }
  }

  // Epilogue: lane holds rows r0+g*16+mr; cols wv*64+q*8..+7 (acc[g][0],acc[g][1])
  // and wv*64+32+q*8..+7 (acc[g][2],acc[g][3]) -> two half8 stores per row.
  const int cb = wv * 64 + q * 8;
  float4 bva0, bva1, bvb0, bvb1;
  if (bias) {
    bva0 = *(const float4*)&bias[cb];      bva1 = *(const float4*)&bias[cb + 4];
    bvb0 = *(const float4*)&bias[cb + 32]; bvb1 = *(const float4*)&bias[cb + 36];
  } else {
    bva0.x = bva0.y = bva0.z = bva0.w = 0.f; bva1 = bva0; bvb0 = bva0; bvb1 = bva0;
  }
  float sv[4];
#pragma unroll
  for (int g = 0; g < 4; ++g) {
    int row = r0 + g * 16 + mr;
    sv[g] = (scale && row < M) ? scale[row] : 1.f;
  }
#pragma unroll
  for (int g = 0; g < 4; ++g) {
    int row = r0 + g * 16 + mr;
    if (row < M) {
      half8 o;
#pragma unroll
      for (int r = 0; r < 4; ++r) {
        float v0 = acc[g][0][r] + (&bva0.x)[r];
        float v1 = acc[g][1][r] + (&bva1.x)[r];
        if (mode == 1) { v0 = tanhf(v0); v1 = tanhf(v1); }
        o[r] = (_Float16)(v0 * sv[g]);
        o[4 + r] = (_Float16)(v1 * sv[g]);
      }
      *(half8*)&C[(size_t)row * HID + cb] = o;
#pragma unroll
      for (int r = 0; r < 4; ++r) {
        float v0 = acc[g][2][r] + (&bvb0.x)[r];
        float v1 = acc[g][3][r] + (&bvb1.x)[r];
        if (mode == 1) { v0 = tanhf(v0); v1 = tanhf(v1); }
        o[r] = (_Float16)(v0 * sv[g]);
        o[4 + r] = (_Float16)(v1 * sv[g]);
      }
      *(half8*)&C[(size_t)row * HID + cb + 32] = o;
    }
  }
}

// ---------------- CSR build (fixed-stride, no scan) ------------------------------
__global__ void zero_int_kernel(int* p, int n, unsigned* gmax) {
  int i = blockIdx.x * 256 + threadIdx.x;
  if (i < n) p[i] = 0;
  if (blockIdx.x == 0 && threadIdx.x < 8) gmax[threadIdx.x] = 0u;
}
__global__ void fill_kernel(const int* __restrict__ src, const int* __restrict__ dst,
                            int* __restrict__ cur, int* __restrict__ csr_src, int n) {
  int i = blockIdx.x * 256 + threadIdx.x;
  if (i < n) {
    int d = dst[i];
    int slot = atomicAdd(&cur[d], 1);
    if (slot < DEGMAX) csr_src[(size_t)d * DEGMAX + slot] = src[i];
  }
}
__global__ void dinv_kernel(const int* __restrict__ deg, float* __restrict__ dinv, int n) {
  int i = blockIdx.x * 256 + threadIdx.x;
  if (i < n) dinv[i] = rsqrtf((float)(deg[i] + 1));
}

// ---------------- GCN aggregation (pull), bias+ReLU fused ------------------------
// PRESCALED=1: hlin rows already carry dinv[row] (GEMM epilogue scale), neighbor
// update is pure load+add. PRESCALED=0 (hoisted GCN0): apply dinv[s] per neighbor.
// Software-pipelined: next index int4 + next feature rows issued before
// accumulating the current group.
template <int PRESCALED>
__global__ __launch_bounds__(256) void gcn_agg_kernel(
    const _Float16* __restrict__ hlin, const int* __restrict__ deg,
    const int* __restrict__ csr_src, const float* __restrict__ dinv,
    const float* __restrict__ bias, _Float16* __restrict__ out) {
  int w = (int)((blockIdx.x * blockDim.x + threadIdx.x) >> 6);
  int lane = threadIdx.x & 63;
  if (w >= N_NODES) return;
  float dv = dinv[w];
  half4 hv = ((const half4*)(hlin + (size_t)w * HID))[lane];
  float selfs = PRESCALED ? 1.f : dv;
  float A0 = (float)hv[0] * selfs, A1 = (float)hv[1] * selfs,
        A2 = (float)hv[2] * selfs, A3 = (float)hv[3] * selfs;
  float B0 = 0.f, B1 = 0.f, B2 = 0.f, B3 = 0.f;
  float C0 = 0.f, C1 = 0.f, C2 = 0.f, C3 = 0.f;
  float D0 = 0.f, D1 = 0.f, D2 = 0.f, D3 = 0.f;
  int dg = deg[w];
  if (dg > DEGMAX) dg = DEGMAX;
  const int* sp = csr_src + (size_t)w * DEGMAX;
  int s = 0;
  if (dg >= 4) {
    int4 iv = *(const int4*)sp;
    half4 p0 = ((const half4*)(hlin + (size_t)iv.x * HID))[lane];
    half4 p1 = ((const half4*)(hlin + (size_t)iv.y * HID))[lane];
    half4 p2 = ((const half4*)(hlin + (size_t)iv.z * HID))[lane];
    half4 p3 = ((const half4*)(hlin + (size_t)iv.w * HID))[lane];
    float e0 = 1.f, e1 = 1.f, e2 = 1.f, e3 = 1.f;
    if (!PRESCALED) { e0 = dinv[iv.x]; e1 = dinv[iv.y]; e2 = dinv[iv.z]; e3 = dinv[iv.w]; }
    for (s = 4; s + 4 <= dg; s += 4) {
      int4 nx = *(const int4*)(sp + s);
      half4 q0 = ((const half4*)(hlin + (size_t)nx.x * HID))[lane];
      half4 q1 = ((const half4*)(hlin + (size_t)nx.y * HID))[lane];
      half4 q2 = ((const half4*)(hlin + (size_t)nx.z * HID))[lane];
      half4 q3 = ((const half4*)(hlin + (size_t)nx.w * HID))[lane];
      float f0 = 1.f, f1 = 1.f, f2 = 1.f, f3 = 1.f;
      if (!PRESCALED) { f0 = dinv[nx.x]; f1 = dinv[nx.y]; f2 = dinv[nx.z]; f3 = dinv[nx.w]; }
      if (PRESCALED) {
        A0 += (float)p0[0]; A1 += (float)p0[1]; A2 += (float)p0[2]; A3 += (float)p0[3];
        B0 += (float)p1[0]; B1 += (float)p1[1]; B2 += (float)p1[2]; B3 += (float)p1[3];
        C0 += (float)p2[0]; C1 += (float)p2[1]; C2 += (float)p2[2]; C3 += (float)p2[3];
        D0 += (float)p3[0]; D1 += (float)p3[1]; D2 += (float)p3[2]; D3 += (float)p3[3];
      } else {
        A0 += (float)p0[0] * e0; A1 += (float)p0[1] * e0; A2 += (float)p0[2] * e0; A3 += (float)p0[3] * e0;
        B0 += (float)p1[0] * e1; B1 += (float)p1[1] * e1; B2 += (float)p1[2] * e1; B3 += (float)p1[3] * e1;
        C0 += (float)p2[0] * e2; C1 += (float)p2[1] * e2; C2 += (float)p2[2] * e2; C3 += (float)p2[3] * e2;
        D0 += (float)p3[0] * e3; D1 += (float)p3[1] * e3; D2 += (float)p3[2] * e3; D3 += (float)p3[3] * e3;
      }
      p0 = q0; p1 = q1; p2 = q2; p3 = q3;
      e0 = f0; e1 = f1; e2 = f2; e3 = f3;
    }
    if (PRESCALED) {
      A0 += (float)p0[0]; A1 += (float)p0[1]; A2 += (float)p0[2]; A3 += (float)p0[3];
      B0 += (float)p1[0]; B1 += (float)p1[1]; B2 += (float)p1[2]; B3 += (float)p1[3];
      C0 += (float)p2[0]; C1 += (float)p2[1]; C2 += (float)p2[2]; C3 += (float)p2[3];
      D0 += (float)p3[0]; D1 += (float)p3[1]; D2 += (float)p3[2]; D3 += (float)p3[3];
    } else {
      A0 += (float)p0[0] * e0; A1 += (float)p0[1] * e0; A2 += (float)p0[2] * e0; A3 += (float)p0[3] * e0;
      B0 += (float)p1[0] * e1; B1 += (float)p1[1] * e1; B2 += (float)p1[2] * e1; B3 += (float)p1[3] * e1;
      C0 += (float)p2[0] * e2; C1 += (float)p2[1] * e2; C2 += (float)p2[2] * e2; C3 += (float)p2[3] * e2;
      D0 += (float)p3[0] * e3; D1 += (float)p3[1] * e3; D2 += (float)p3[2] * e3; D3 += (float)p3[3] * e3;
    }
  }
  for (; s < dg; ++s) {
    int sc = sp[s];
    float nr = PRESCALED ? 1.f : dinv[sc];
    half4 v = ((const half4*)(hlin + (size_t)sc * HID))[lane];
    A0 += (float)v[0] * nr; A1 += (float)v[1] * nr;
    A2 += (float)v[2] * nr; A3 += (float)v[3] * nr;
  }
  float4 b = ((const float4*)bias)[lane];
  half4 r;
  r[0] = (_Float16)fmaxf((A0 + B0 + C0 + D0) * dv + b.x, 0.f);
  r[1] = (_Float16)fmaxf((A1 + B1 + C1 + D1) * dv + b.y, 0.f);
  r[2] = (_Float16)fmaxf((A2 + B2 + C2 + D2) * dv + b.z, 0.f);
  r[3] = (_Float16)fmaxf((A3 + B3 + C3 + D3) * dv + b.w, 0.f);
  ((half4*)(out + (size_t)w * HID))[lane] = r;
}

// ---------------- GAT: per-node attention coefficients ---------------------------
__global__ __launch_bounds__(256) void gat_prep_kernel(
    const _Float16* __restrict__ hlin, const float* __restrict__ a_src,
    const float* __restrict__ a_dst, float* __restrict__ asad) {
  int w = (int)((blockIdx.x * blockDim.x + threadIdx.x) >> 6);
  int lane = threadIdx.x & 63;
  if (w >= N_NODES) return;
  half4 h = ((const half4*)(hlin + (size_t)w * HID))[lane];
  float4 s4 = ((const float4*)a_src)[lane];
  float4 d4 = ((const float4*)a_dst)[lane];
  float hx = h[0], hy = h[1], hz = h[2], hw = h[3];
  float ps = hx * s4.x + hy * s4.y + hz * s4.z + hw * s4.w;
  float pd = hx * d4.x + hy * d4.y + hz * d4.z + hw * d4.w;
  for (int o = 1; o < 8; o <<= 1) { ps += __shfl_xor(ps, o, 64); pd += __shfl_xor(pd, o, 64); }
  if ((lane & 7) == 0) {
    int hh = lane >> 3;
    asad[(size_t)w * 16 + hh] = ps;
    asad[(size_t)w * 16 + 8 + hh] = pd;
  }
}

// ---------------- per-head global max of a_src projections -----------------------
__global__ __launch_bounds__(256) void gmax_kernel(const float* __restrict__ asad,
                                                   unsigned* __restrict__ gmax) {
  int t = threadIdx.x;
  int h = t & 7;
  float m = -1e30f;
  for (int n = blockIdx.x * 32 + (t >> 3); n < N_NODES; n += gridDim.x * 32)
    m = fmaxf(m, asad[(size_t)n * 16 + h]);
  m = fmaxf(m, __shfl_xor(m, 8, 64));
  m = fmaxf(m, __shfl_xor(m, 16, 64));
  m = fmaxf(m, __shfl_xor(m, 32, 64));
  if ((t & 63) < 8) atomicMax(&gmax[h], f2ord(m));
}

static __device__ __forceinline__ float lrelu(float e) {
  return e > 0.f ? e : 0.2f * e;
}

// ---------------- GAT aggregation + LayerNorm + weighted accumulate --------------
__global__ __launch_bounds__(256) void gat_agg_kernel(
    const _Float16* __restrict__ hlin, const int* __restrict__ deg,
    const int* __restrict__ csr_src, const float* __restrict__ asad,
    const unsigned* __restrict__ gmax, const float* __restrict__ bias,
    const float* __restrict__ lng, const float* __restrict__ lnb,
    const float* __restrict__ wsel, int kk, float* __restrict__ dout) {
  int w = (int)((blockIdx.x * blockDim.x + threadIdx.x) >> 6);
  int lane = threadIdx.x & 63;
  if (w >= N_NODES) return;
  int head = lane >> 3;
  int e7 = lane & 7;
  int gsel = lane >> 4;
  float ad_d = asad[(size_t)w * 16 + 8 + head];
  float m = lrelu(ord2f(gmax[head]) + ad_d);
  float e_self = lrelu(asad[(size_t)w * 16 + head] + ad_d);
  float ad_e = __shfl(ad_d, e7 << 3, 64);
  float m_e = __shfl(m, e7 << 3, 64);
  int dg = deg[w];
  if (dg > DEGMAX) dg = DEGMAX;
  const int* sp = csr_src + (size_t)w * DEGMAX;
  float lA = __expf(e_self - m), lB = 0.f, lC = 0.f, lD = 0.f;
  half4 hv = ((const half4*)(hlin + (size_t)w * HID))[lane];
  float A0 = (float)hv[0] * lA, A1 = (float)hv[1] * lA,
        A2 = (float)hv[2] * lA, A3 = (float)hv[3] * lA;
  float B0 = 0.f, B1 = 0.f, B2 = 0.f, B3 = 0.f;
  float C0 = 0.f, C1 = 0.f, C2 = 0.f, C3 = 0.f;
  float D0 = 0.f, D1 = 0.f, D2 = 0.f, D3 = 0.f;
  int ng = (dg + 3) >> 2;
  int4 iv;
  if (ng) iv = *(const int4*)sp;
  for (int gi = 0; gi < ng; ++gi) {
    int s4 = gi << 2;
    int rem = dg - s4;
    bool tail = rem < 4;
    if (tail) {
      if (rem < 2) iv.y = iv.x;
      if (rem < 3) iv.z = iv.x;
      iv.w = iv.x;
    }
    int nsel = gsel == 0 ? iv.x : gsel == 1 ? iv.y : gsel == 2 ? iv.z : iv.w;
    float av = asad[(size_t)nsel * 16 + e7];
    half4 v0 = ((const half4*)(hlin + (size_t)iv.x * HID))[lane];
    half4 v1 = ((const half4*)(hlin + (size_t)iv.y * HID))[lane];
    half4 v2 = ((const half4*)(hlin + (size_t)iv.z * HID))[lane];
    half4 v3 = ((const half4*)(hlin + (size_t)iv.w * HID))[lane];
    int4 nx = iv;
    if (gi + 1 < ng) nx = *(const int4*)(sp + s4 + 4);
    float ve = __expf(lrelu(av + ad_e) - m_e);
    float w0 = __shfl(ve, head, 64);
    float w1 = __shfl(ve, 16 + head, 64);
    float w2 = __shfl(ve, 32 + head, 64);
    float w3 = __shfl(ve, 48 + head, 64);
    if (tail) {
      if (rem < 2) w1 = 0.f;
      if (rem < 3) w2 = 0.f;
      w3 = 0.f;
    }
    lA += w0; lB += w1; lC += w2; lD += w3;
    A0 += (float)v0[0] * w0; A1 += (float)v0[1] * w0; A2 += (float)v0[2] * w0; A3 += (float)v0[3] * w0;
    B0 += (float)v1[0] * w1; B1 += (float)v1[1] * w1; B2 += (float)v1[2] * w1; B3 += (float)v1[3] * w1;
    C0 += (float)v2[0] * w2; C1 += (float)v2[1] * w2; C2 += (float)v2[2] * w2; C3 += (float)v2[3] * w2;
    D0 += (float)v3[0] * w3; D1 += (float)v3[1] * w3; D2 += (float)v3[2] * w3; D3 += (float)v3[3] * w3;
    iv = nx;
  }
  float inv = 1.f / (lA + lB + lC + lD);
  float4 b = ((const float4*)bias)[lane];
  float vx = (A0 + B0 + C0 + D0) * inv + b.x;
  float vy = (A1 + B1 + C1 + D1) * inv + b.y;
  float vz = (A2 + B2 + C2 + D2) * inv + b.z;
  float vw = (A3 + B3 + C3 + D3) * inv + b.w;
  float ssum = vx + vy + vz + vw;
  for (int o = 1; o < 64; o <<= 1) ssum += __shfl_xor(ssum, o, 64);
  float mu = ssum * (1.f / HID);
  float dx = vx - mu, dy = vy - mu, dz = vz - mu, dw = vw - mu;
  float qq = dx * dx + dy * dy + dz * dz + dw * dw;
  for (int o = 1; o < 64; o <<= 1) qq += __shfl_xor(qq, o, 64);
  float rs = rsqrtf(qq * (1.f / HID) + 1e-5f);
  float4 g4 = ((const float4*)lng)[lane];
  float4 b4 = ((const float4*)lnb)[lane];
  float wk = wsel[(size_t)w * 4 + kk];
  float4 r;
  r.x = (dx * rs * g4.x + b4.x) * wk;
  r.y = (dy * rs * g4.y + b4.y) * wk;
  r.z = (dz * rs * g4.z + b4.z) * wk;
  r.w = (dw * rs * g4.w + b4.w) * wk;
  float4* dp = (float4*)(dout + (size_t)w * HID) + lane;
  if (kk == 0) {
    *dp = r;
  } else {
    float4 old = *dp;
    old.x += r.x; old.y += r.y; old.z += r.z; old.w += r.w;
    *dp = old;
  }
}

// ---------------- fusion weights: logits = t @ W2 + b2, softmax(K=4) --------------
__global__ __launch_bounds__(256) void fusw_kernel(
    const _Float16* __restrict__ t, const float* __restrict__ W2,
    const float* __restrict__ b2, float* __restrict__ wout) {
  int w = (int)((blockIdx.x * blockDim.x + threadIdx.x) >> 6);
  int lane = threadIdx.x & 63;
  if (w >= N_NODES) return;
  half4 t4h = ((const half4*)(t + (size_t)w * HID))[lane];
  float tx = t4h[0], ty = t4h[1], tz = t4h[2], tw = t4h[3];
  int c = lane * 4;
  float4 w0 = ((const float4*)W2)[c + 0];
  float4 w1 = ((const float4*)W2)[c + 1];
  float4 w2 = ((const float4*)W2)[c + 2];
  float4 w3 = ((const float4*)W2)[c + 3];
  float p0 = tx * w0.x + ty * w1.x + tz * w2.x + tw * w3.x;
  float p1 = tx * w0.y + ty * w1.y + tz * w2.y + tw * w3.y;
  float p2 = tx * w0.z + ty * w1.z + tz * w2.z + tw * w3.z;
  float p3 = tx * w0.w + ty * w1.w + tz * w2.w + tw * w3.w;
  for (int o = 1; o < 64; o <<= 1) {
    p0 += __shfl_xor(p0, o, 64); p1 += __shfl_xor(p1, o, 64);
    p2 += __shfl_xor(p2, o, 64); p3 += __shfl_xor(p3, o, 64);
  }
  if (lane == 0) {
    p0 += b2[0]; p1 += b2[1]; p2 += b2[2]; p3 += b2[3];
    float mx = fmaxf(fmaxf(p0, p1), fmaxf(p2, p3));
    float e0 = __expf(p0 - mx), e1 = __expf(p1 - mx), e2 = __expf(p2 - mx), e3 = __expf(p3 - mx);
    float inv = 1.f / (e0 + e1 + e2 + e3);
    float4 r; r.x = e0 * inv; r.y = e1 * inv; r.z = e2 * inv; r.w = e3 * inv;
    ((float4*)wout)[w] = r;
  }
}

extern "C" void kernel_launch(void* const* d_in, const int* in_sizes, int n_in,
                              void* d_out, int out_size, void* d_ws, size_t ws_size,
                              hipStream_t stream) {
  const float* x      = (const float*)d_in[0];
  const float* style  = (const float*)d_in[1];
  const float* stress = (const float*)d_in[2];
  const int* edges[4] = {(const int*)d_in[3], (const int*)d_in[4],
                         (const int*)d_in[5], (const int*)d_in[6]};
  const float* gW0 = (const float*)d_in[7];
  const float* gb0 = (const float*)d_in[8];
  const float* gW1 = (const float*)d_in[9];
  const float* gb1 = (const float*)d_in[10];
  const float* gW2 = (const float*)d_in[11];
  const float* gb2 = (const float*)d_in[12];
  const float* aW  = (const float*)d_in[13];
  const float* aas = (const float*)d_in[14];
  const float* aad = (const float*)d_in[15];
  const float* ab  = (const float*)d_in[16];
  const float* lg  = (const float*)d_in[17];
  const float* lb  = (const float*)d_in[18];
  const float* fW1 = (const float*)d_in[19];
  const float* fb1 = (const float*)d_in[20];
  const float* fW2 = (const float*)d_in[21];
  const float* fb2 = (const float*)d_in[22];
  float* out = (float*)d_out;
  (void)in_sizes; (void)n_in; (void)out_size;

  char* wsp = (char*)d_ws;
  size_t off = 0;
  auto alloc = [&](size_t bytes) -> void* {
    void* p = wsp + off;
    off += (bytes + 255) & ~(size_t)255;
    return p;
  };
  auto al = [](size_t b) { return (b + 255) & ~(size_t)255; };

  const size_t sz_hact = (size_t)N_NODES * HID * 2;
  const size_t sz_xh   = (size_t)N_NODES * IN_DIM * 2;
  const size_t sz_csr  = (size_t)N_NODES * DEGMAX * 4;
  const size_t sz_hlin0 = (size_t)4 * N_NODES * HID * 2;  // 102.4 MB

  const size_t fixed = al(sz_hact) * 2 + al(sz_xh) + al((size_t)WT_TOT * 2) +
                       al((size_t)N_NODES * 16) + al((size_t)N_NODES * 4) * 2 +
                       al((size_t)N_NODES * 64) + al(256);
  const size_t need_hoist = fixed + al(sz_csr) + al(sz_hlin0);
  const bool hoist = ws_size >= need_hoist;

  _Float16* h_act = (_Float16*)alloc(sz_hact);
  _Float16* h_lin = (_Float16*)alloc(sz_hact);
  _Float16* x_h   = (_Float16*)alloc(sz_xh);
  _Float16* wtall = (_Float16*)alloc((size_t)WT_TOT * 2);
  float* wsel = (float*)alloc((size_t)N_NODES * 16);
  float* dinv = (float*)alloc((size_t)N_NODES * 4);
  int* cur = (int*)alloc((size_t)N_NODES * 4);
  float* asad = (float*)alloc((size_t)N_NODES * 64);
  unsigned* gmax = (unsigned*)alloc(256);
  _Float16* ctx_h;
  int* csr_src;
  _Float16* h_lin0 = nullptr;
  if (hoist) {
    csr_src = (int*)alloc(sz_csr);
    char* region = (char*)alloc(sz_hlin0);  // ctx_h lives here until fusion GEMM done
    ctx_h = (_Float16*)region;
    h_lin0 = (_Float16*)region;
  } else {
    char* shared_region = (char*)alloc(sz_xh);  // 51.2 MB: ctx then csr
    ctx_h = (_Float16*)shared_region;
    csr_src = (int*)shared_region;
  }

  dim3 blk(256);
  const int nodeWaveBlocks = N_NODES / 4;
  const int nBlocksN = (N_NODES + 255) / 256;
  const int nBlocksE = (NEDGE + 255) / 256;
  const int gemmBlocks = (N_NODES + 63) / 64;  // 782

  // ---- one-time conversions ----
  conv_f2h_kernel<<<(N_NODES * IN_DIM / 4 + 255) / 256, blk, 0, stream>>>(x, x_h, N_NODES * IN_DIM / 4);
  conv_ctx_kernel<<<(N_NODES * 128 + 255) / 256, blk, 0, stream>>>(style, stress, ctx_h);
  wconv_all_kernel<<<(WT_TOT + 255) / 256, blk, 0, stream>>>(fW1, gW0, gW1, gW2, aW, wtall);

  // ---- fusion gate ----
  gemm_f16_kernel<512><<<gemmBlocks, blk, 0, stream>>>(ctx_h, wtall + WT_FUS, fb1, h_lin,
                                                       N_NODES, 1, nullptr, 0, 0);
  fusw_kernel<<<nodeWaveBlocks, blk, 0, stream>>>(h_lin, fW2, fb2, wsel);

  // ---- hoisted GCN0 linear: x @ W0_k for all 4 topologies in one dispatch ----
  if (hoist) {
    gemm_f16_kernel<512><<<dim3(gemmBlocks, 4), blk, 0, stream>>>(
        x_h, wtall + WT_G0, nullptr, h_lin0, N_NODES, 0, nullptr,
        131072, N_NODES * HID);
  }

  for (int k = 0; k < TOPO; ++k) {
    const int* srcp = edges[k];
    const int* dstp = edges[k] + NEDGE;
    zero_int_kernel<<<nBlocksN, blk, 0, stream>>>(cur, N_NODES, gmax);
    fill_kernel<<<nBlocksE, blk, 0, stream>>>(srcp, dstp, cur, csr_src, NEDGE);
    dinv_kernel<<<nBlocksN, blk, 0, stream>>>(cur, dinv, N_NODES);

    // GCN0 (512 -> 256)
    if (hoist) {
      gcn_agg_kernel<0><<<nodeWaveBlocks, blk, 0, stream>>>(
          h_lin0 + (size_t)k * N_NODES * HID, cur, csr_src, dinv,
          gb0 + (size_t)k * HID, h_act);
    } else {
      gemm_f16_kernel<512><<<gemmBlocks, blk, 0, stream>>>(
          x_h, wtall + WT_G0 + (size_t)k * 131072, nullptr, h_lin, N_NODES, 0, dinv, 0, 0);
      gcn_agg_kernel<1><<<nodeWaveBlocks, blk, 0, stream>>>(h_lin, cur, csr_src, dinv,
                                                            gb0 + (size_t)k * HID, h_act);
    }
    // GCN1
    gemm_f16_kernel<256><<<gemmBlocks, blk, 0, stream>>>(
        h_act, wtall + WT_G1 + (size_t)k * 65536, nullptr, h_lin, N_NODES, 0, dinv, 0, 0);
    gcn_agg_kernel<1><<<nodeWaveBlocks, blk, 0, stream>>>(h_lin, cur, csr_src, dinv,
                                                          gb1 + (size_t)k * HID, h_act);
    // GCN2
    gemm_f16_kernel<256><<<gemmBlocks, blk, 0, stream>>>(
        h_act, wtall + WT_G2 + (size_t)k * 65536, nullptr, h_lin, N_NODES, 0, dinv, 0, 0);
    gcn_agg_kernel<1><<<nodeWaveBlocks, blk, 0, stream>>>(h_lin, cur, csr_src, dinv,
                                                          gb2 + (size_t)k * HID, h_act);
    // GAT (unscaled linear output)
    gemm_f16_kernel<256><<<gemmBlocks, blk, 0, stream>>>(
        h_act, wtall + WT_AW + (size_t)k * 65536, nullptr, h_lin, N_NODES, 0, nullptr, 0, 0);
    gat_prep_kernel<<<nodeWaveBlocks, blk, 0, stream>>>(h_lin, aas + (size_t)k * HID,
                                                        aad + (size_t)k * HID, asad);
    gmax_kernel<<<64, blk, 0, stream>>>(asad, gmax);
    gat_agg_kernel<<<nodeWaveBlocks, blk, 0, stream>>>(h_lin, cur, csr_src, asad, gmax,
                                                       ab + (size_t)k * HID,
                                                       lg + (size_t)k * HID,
                                                       lb + (size_t)k * HID,
                                                       wsel, k, out);
  }
}

// Round 6
// 1741.256 us; speedup vs baseline: 1.2636x; 1.0486x over previous
//
#include <hip/hip_runtime.h>
#include <hip/hip_bf16.h>
#include <cstdint>

#define N_NODES 50000
#define IN_DIM  512
#define HID     256
#define NEDGE   600000
#define TOPO    4
#define DEGMAX  96

typedef __attribute__((ext_vector_type(4))) float floatx4;
typedef _Float16 half4 __attribute__((ext_vector_type(4)));
typedef _Float16 half8 __attribute__((ext_vector_type(8)));

// ---------------- ordered-float <-> uint for atomicMax ---------------------------
static __device__ __forceinline__ unsigned f2ord(float f) {
  unsigned b = __float_as_uint(f);
  return (b & 0x80000000u) ? ~b : (b | 0x80000000u);
}
static __device__ __forceinline__ float ord2f(unsigned u) {
  unsigned b = (u & 0x80000000u) ? (u & 0x7fffffffu) : ~u;
  return __uint_as_float(b);
}

// ---------------- f32 -> f16 converters (run once) -------------------------------
__global__ void conv_f2h_kernel(const float* __restrict__ src, _Float16* __restrict__ dst, int n4) {
  int i = blockIdx.x * 256 + threadIdx.x;
  if (i < n4) {
    float4 v = ((const float4*)src)[i];
    half4 h;
    h[0] = (_Float16)v.x; h[1] = (_Float16)v.y; h[2] = (_Float16)v.z; h[3] = (_Float16)v.w;
    ((half4*)dst)[i] = h;
  }
}

// ctx = [style | stress] -> fp16 [N][512]
__global__ void conv_ctx_kernel(const float* __restrict__ style, const float* __restrict__ stress,
                                _Float16* __restrict__ dst) {
  int i = blockIdx.x * 256 + threadIdx.x;
  if (i >= N_NODES * 128) return;
  int n = i >> 7, c4 = i & 127;
  int c = c4 * 4;
  const float* s = (c < 256) ? (style + (size_t)n * 256 + c) : (stress + (size_t)n * 256 + (c - 256));
  float4 v = *(const float4*)s;
  half4 h;
  h[0] = (_Float16)v.x; h[1] = (_Float16)v.y; h[2] = (_Float16)v.z; h[3] = (_Float16)v.w;
  ((half4*)(dst + (size_t)n * 512))[c4] = h;
}

// ---- all 17 weight matrices -> fp16, transposed to Wt[n][kd], one dispatch ------
#define WT_FUS 0
#define WT_G0  131072
#define WT_G1  655360
#define WT_G2  917504
#define WT_AW  1179648
#define WT_TOT 1441792
__global__ void wconv_all_kernel(const float* __restrict__ fW1, const float* __restrict__ gW0,
                                 const float* __restrict__ gW1, const float* __restrict__ gW2,
                                 const float* __restrict__ aW, _Float16* __restrict__ wt) {
  int idx = blockIdx.x * 256 + threadIdx.x;
  if (idx >= WT_TOT) return;
  const float* src;
  int local, sh;
  if (idx < WT_G0) { src = fW1; sh = 9; local = idx; }
  else if (idx < WT_G1) { int r = idx - WT_G0; src = gW0 + (size_t)(r >> 17) * 131072; sh = 9; local = r & 131071; }
  else if (idx < WT_G2) { int r = idx - WT_G1; src = gW1 + (size_t)(r >> 16) * 65536; sh = 8; local = r & 65535; }
  else if (idx < WT_AW) { int r = idx - WT_G2; src = gW2 + (size_t)(r >> 16) * 65536; sh = 8; local = r & 65535; }
  else { int r = idx - WT_AW; src = aW + (size_t)(r >> 16) * 65536; sh = 8; local = r & 65535; }
  int n = local >> sh;
  int kd = local & ((1 << sh) - 1);
  wt[idx] = (_Float16)src[(size_t)kd * 256 + n];
}

// ---------------- GEMM: C[M,256] = A[M,KD] @ W[KD,256], fp16 MFMA ----------------
// Tile 128 rows x 256 cols per block (256 threads, 4 waves; wave wv owns cols
// [wv*64, wv*64+64), 8 row-groups). Row-tile 128 doubles MFMA per barrier
// (32/K-iter/wave) and halves B-loads per MFMA — the 2-barrier K-loop is
// drain-bound, so amortization is the lever.
// A staged in LDS in fragment order (2 slots/thread, conflict-free b128 both
// ways); B frags direct global->reg with 1-iter prefetch; LDS double-buffered.
// b-frag t covers weight cols wcol(t,mr) = wv*64+(t>>1)*32+(mr>>2)*8+(mr&3)+(t&1)*4
// so lane (mr,q) holds 8 CONSECUTIVE output cols per t-pair -> half8 stores (R4:
// killed the 1.9x write amplification).
// blockIdx.y selects a weight/output pair (batched GCN0). mode 1 = tanh(x+bias).
// scale: optional per-row multiplier (GCN dinv pre-scaling).
template <int KD>
__global__ __launch_bounds__(256, 2) void gemm_f16_kernel(
    const _Float16* __restrict__ A, const _Float16* __restrict__ Wt0,
    const float* __restrict__ bias, _Float16* __restrict__ C0, int M, int mode,
    const float* __restrict__ scale, int wt_stride, int c_stride) {
  constexpr int NIT = KD / 32;
  const _Float16* Wt = Wt0 + (size_t)blockIdx.y * wt_stride;
  _Float16* C = C0 + (size_t)blockIdx.y * c_stride;
  __shared__ __align__(16) _Float16 As[2][4096];  // 8 frags x 64 lanes x 8 halves
  const int tid = threadIdx.x;
  const int lane = tid & 63;
  const int wv = tid >> 6;
  const int mr = lane & 15;
  const int q = (lane >> 4) & 3;
  const int r0 = blockIdx.x * 128;

  // A staging: thread t owns frag-slots t and t+256; slot s -> g=s>>6, mr=s&15,
  // q=(s>>4)&3 (q identical for both slots).
  int row0 = r0 + ((tid >> 6) * 16) + (tid & 15);
  int row1 = r0 + (((tid + 256) >> 6) * 16) + (tid & 15);
  if (row0 > M - 1) row0 = M - 1;
  if (row1 > M - 1) row1 = M - 1;
  const _Float16* pa0 = A + (size_t)row0 * KD + ((tid >> 4) & 3) * 8;
  const _Float16* pa1 = A + (size_t)row1 * KD + ((tid >> 4) & 3) * 8;
  const _Float16* pb[4];
#pragma unroll
  for (int t = 0; t < 4; ++t) {
    int wcol = wv * 64 + (t >> 1) * 32 + ((mr >> 2) * 8) + (mr & 3) + (t & 1) * 4;
    pb[t] = Wt + (size_t)wcol * KD + q * 8;
  }

  floatx4 acc[8][4];
#pragma unroll
  for (int g = 0; g < 8; ++g)
#pragma unroll
    for (int t = 0; t < 4; ++t) acc[g][t] = (floatx4){0.f, 0.f, 0.f, 0.f};

  half8 a0, a0b, a1, a1b, b0[4], b1[4];
  a0 = *(const half8*)pa0; a0b = *(const half8*)pa1; pa0 += 32; pa1 += 32;
#pragma unroll
  for (int t = 0; t < 4; ++t) { b0[t] = *(const half8*)pb[t]; pb[t] += 32; }
  *(half8*)&As[0][(unsigned)tid * 8] = a0;
  *(half8*)&As[0][(unsigned)(tid + 256) * 8] = a0b;
  if (NIT > 1) { a1 = *(const half8*)pa0; a1b = *(const half8*)pa1; pa0 += 32; pa1 += 32; }
  __syncthreads();

#pragma unroll 1
  for (int it = 0; it < NIT; it += 2) {
    // ---- even half: compute from As[0] with b0 ----
    if (it + 1 < NIT) {
      *(half8*)&As[1][(unsigned)tid * 8] = a1;
      *(half8*)&As[1][(unsigned)(tid + 256) * 8] = a1b;
#pragma unroll
      for (int t = 0; t < 4; ++t) { b1[t] = *(const half8*)pb[t]; pb[t] += 32; }
      if (it + 2 < NIT) { a0 = *(const half8*)pa0; a0b = *(const half8*)pa1; pa0 += 32; pa1 += 32; }
    }
    {
#pragma unroll
      for (int g = 0; g < 8; ++g) {
        half8 af = *(const half8*)&As[0][(g * 64 + lane) * 8];
#pragma unroll
        for (int t = 0; t < 4; ++t)
          acc[g][t] = __builtin_amdgcn_mfma_f32_16x16x32_f16(b0[t], af, acc[g][t], 0, 0, 0);
      }
    }
    if (it + 1 < NIT) {
      __syncthreads();
      // ---- odd half: compute from As[1] with b1 ----
      if (it + 2 < NIT) {
        *(half8*)&As[0][(unsigned)tid * 8] = a0;
        *(half8*)&As[0][(unsigned)(tid + 256) * 8] = a0b;
#pragma unroll
        for (int t = 0; t < 4; ++t) { b0[t] = *(const half8*)pb[t]; pb[t] += 32; }
        if (it + 3 < NIT) { a1 = *(const half8*)pa0; a1b = *(const half8*)pa1; pa0 += 32; pa1 += 32; }
      }
#pragma unroll
      for (int g = 0; g < 8; ++g) {
        half8 af = *(const half8*)&As[1][(g * 64 + lane) * 8];
#pragma unroll
        for (int t = 0; t < 4; ++t)
          acc[g][t] = __builtin_amdgcn_mfma_f32_16x16x32_f16(b1[t], af, acc[g][t], 0, 0, 0);
      }
      if (it + 2 < NIT) __syncthreads();
    }
  }

  // Epilogue: lane holds rows r0+g*16+mr; cols wv*64+q*8..+7 (acc[g][0..1]) and
  // wv*64+32+q*8..+7 (acc[g][2..3]) -> two half8 stores per row.
  const int cb = wv * 64 + q * 8;
  float4 bva0, bva1, bvb0, bvb1;
  if (bias) {
    bva0 = *(const float4*)&bias[cb];      bva1 = *(const float4*)&bias[cb + 4];
    bvb0 = *(const float4*)&bias[cb + 32]; bvb1 = *(const float4*)&bias[cb + 36];
  } else {
    bva0.x = bva0.y = bva0.z = bva0.w = 0.f; bva1 = bva0; bvb0 = bva0; bvb1 = bva0;
  }
#pragma unroll
  for (int g = 0; g < 8; ++g) {
    int row = r0 + g * 16 + mr;
    if (row < M) {
      float sg = scale ? scale[row] : 1.f;
      half8 o;
#pragma unroll
      for (int r = 0; r < 4; ++r) {
        float v0 = acc[g][0][r] + (&bva0.x)[r];
        float v1 = acc[g][1][r] + (&bva1.x)[r];
        if (mode == 1) { v0 = tanhf(v0); v1 = tanhf(v1); }
        o[r] = (_Float16)(v0 * sg);
        o[4 + r] = (_Float16)(v1 * sg);
      }
      *(half8*)&C[(size_t)row * HID + cb] = o;
#pragma unroll
      for (int r = 0; r < 4; ++r) {
        float v0 = acc[g][2][r] + (&bvb0.x)[r];
        float v1 = acc[g][3][r] + (&bvb1.x)[r];
        if (mode == 1) { v0 = tanhf(v0); v1 = tanhf(v1); }
        o[r] = (_Float16)(v0 * sg);
        o[4 + r] = (_Float16)(v1 * sg);
      }
      *(half8*)&C[(size_t)row * HID + cb + 32] = o;
    }
  }
}

// ---------------- CSR build (fixed-stride, no scan) ------------------------------
__global__ void zero_int_kernel(int* p, int n, unsigned* gmax) {
  int i = blockIdx.x * 256 + threadIdx.x;
  if (i < n) p[i] = 0;
  if (blockIdx.x == 0 && threadIdx.x < 8) gmax[threadIdx.x] = 0u;
}
__global__ void fill_kernel(const int* __restrict__ src, const int* __restrict__ dst,
                            int* __restrict__ cur, int* __restrict__ csr_src, int n) {
  int i = blockIdx.x * 256 + threadIdx.x;
  if (i < n) {
    int d = dst[i];
    int slot = atomicAdd(&cur[d], 1);
    if (slot < DEGMAX) csr_src[(size_t)d * DEGMAX + slot] = src[i];
  }
}
__global__ void dinv_kernel(const int* __restrict__ deg, float* __restrict__ dinv, int n) {
  int i = blockIdx.x * 256 + threadIdx.x;
  if (i < n) dinv[i] = rsqrtf((float)(deg[i] + 1));
}

// ---------------- GCN aggregation (pull), bias+ReLU fused ------------------------
// PRESCALED=1: hlin rows already carry dinv[row] (GEMM epilogue scale), neighbor
// update is pure load+add. PRESCALED=0 (hoisted GCN0): apply dinv[s] per neighbor.
// Software-pipelined: next index int4 + next feature rows issued before
// accumulating the current group.
template <int PRESCALED>
__global__ __launch_bounds__(256) void gcn_agg_kernel(
    const _Float16* __restrict__ hlin, const int* __restrict__ deg,
    const int* __restrict__ csr_src, const float* __restrict__ dinv,
    const float* __restrict__ bias, _Float16* __restrict__ out) {
  int w = (int)((blockIdx.x * blockDim.x + threadIdx.x) >> 6);
  int lane = threadIdx.x & 63;
  if (w >= N_NODES) return;
  float dv = dinv[w];
  half4 hv = ((const half4*)(hlin + (size_t)w * HID))[lane];
  float selfs = PRESCALED ? 1.f : dv;
  float A0 = (float)hv[0] * selfs, A1 = (float)hv[1] * selfs,
        A2 = (float)hv[2] * selfs, A3 = (float)hv[3] * selfs;
  float B0 = 0.f, B1 = 0.f, B2 = 0.f, B3 = 0.f;
  float C0 = 0.f, C1 = 0.f, C2 = 0.f, C3 = 0.f;
  float D0 = 0.f, D1 = 0.f, D2 = 0.f, D3 = 0.f;
  int dg = deg[w];
  if (dg > DEGMAX) dg = DEGMAX;
  const int* sp = csr_src + (size_t)w * DEGMAX;
  int s = 0;
  if (dg >= 4) {
    int4 iv = *(const int4*)sp;
    half4 p0 = ((const half4*)(hlin + (size_t)iv.x * HID))[lane];
    half4 p1 = ((const half4*)(hlin + (size_t)iv.y * HID))[lane];
    half4 p2 = ((const half4*)(hlin + (size_t)iv.z * HID))[lane];
    half4 p3 = ((const half4*)(hlin + (size_t)iv.w * HID))[lane];
    float e0 = 1.f, e1 = 1.f, e2 = 1.f, e3 = 1.f;
    if (!PRESCALED) { e0 = dinv[iv.x]; e1 = dinv[iv.y]; e2 = dinv[iv.z]; e3 = dinv[iv.w]; }
    for (s = 4; s + 4 <= dg; s += 4) {
      int4 nx = *(const int4*)(sp + s);
      half4 q0 = ((const half4*)(hlin + (size_t)nx.x * HID))[lane];
      half4 q1 = ((const half4*)(hlin + (size_t)nx.y * HID))[lane];
      half4 q2 = ((const half4*)(hlin + (size_t)nx.z * HID))[lane];
      half4 q3 = ((const half4*)(hlin + (size_t)nx.w * HID))[lane];
      float f0 = 1.f, f1 = 1.f, f2 = 1.f, f3 = 1.f;
      if (!PRESCALED) { f0 = dinv[nx.x]; f1 = dinv[nx.y]; f2 = dinv[nx.z]; f3 = dinv[nx.w]; }
      if (PRESCALED) {
        A0 += (float)p0[0]; A1 += (float)p0[1]; A2 += (float)p0[2]; A3 += (float)p0[3];
        B0 += (float)p1[0]; B1 += (float)p1[1]; B2 += (float)p1[2]; B3 += (float)p1[3];
        C0 += (float)p2[0]; C1 += (float)p2[1]; C2 += (float)p2[2]; C3 += (float)p2[3];
        D0 += (float)p3[0]; D1 += (float)p3[1]; D2 += (float)p3[2]; D3 += (float)p3[3];
      } else {
        A0 += (float)p0[0] * e0; A1 += (float)p0[1] * e0; A2 += (float)p0[2] * e0; A3 += (float)p0[3] * e0;
        B0 += (float)p1[0] * e1; B1 += (float)p1[1] * e1; B2 += (float)p1[2] * e1; B3 += (float)p1[3] * e1;
        C0 += (float)p2[0] * e2; C1 += (float)p2[1] * e2; C2 += (float)p2[2] * e2; C3 += (float)p2[3] * e2;
        D0 += (float)p3[0] * e3; D1 += (float)p3[1] * e3; D2 += (float)p3[2] * e3; D3 += (float)p3[3] * e3;
      }
      p0 = q0; p1 = q1; p2 = q2; p3 = q3;
      e0 = f0; e1 = f1; e2 = f2; e3 = f3;
    }
    if (PRESCALED) {
      A0 += (float)p0[0]; A1 += (float)p0[1]; A2 += (float)p0[2]; A3 += (float)p0[3];
      B0 += (float)p1[0]; B1 += (float)p1[1]; B2 += (float)p1[2]; B3 += (float)p1[3];
      C0 += (float)p2[0]; C1 += (float)p2[1]; C2 += (float)p2[2]; C3 += (float)p2[3];
      D0 += (float)p3[0]; D1 += (float)p3[1]; D2 += (float)p3[2]; D3 += (float)p3[3];
    } else {
      A0 += (float)p0[0] * e0; A1 += (float)p0[1] * e0; A2 += (float)p0[2] * e0; A3 += (float)p0[3] * e0;
      B0 += (float)p1[0] * e1; B1 += (float)p1[1] * e1; B2 += (float)p1[2] * e1; B3 += (float)p1[3] * e1;
      C0 += (float)p2[0] * e2; C1 += (float)p2[1] * e2; C2 += (float)p2[2] * e2; C3 += (float)p2[3] * e2;
      D0 += (float)p3[0] * e3; D1 += (float)p3[1] * e3; D2 += (float)p3[2] * e3; D3 += (float)p3[3] * e3;
    }
  }
  for (; s < dg; ++s) {
    int sc = sp[s];
    float nr = PRESCALED ? 1.f : dinv[sc];
    half4 v = ((const half4*)(hlin + (size_t)sc * HID))[lane];
    A0 += (float)v[0] * nr; A1 += (float)v[1] * nr;
    A2 += (float)v[2] * nr; A3 += (float)v[3] * nr;
  }
  float4 b = ((const float4*)bias)[lane];
  half4 r;
  r[0] = (_Float16)fmaxf((A0 + B0 + C0 + D0) * dv + b.x, 0.f);
  r[1] = (_Float16)fmaxf((A1 + B1 + C1 + D1) * dv + b.y, 0.f);
  r[2] = (_Float16)fmaxf((A2 + B2 + C2 + D2) * dv + b.z, 0.f);
  r[3] = (_Float16)fmaxf((A3 + B3 + C3 + D3) * dv + b.w, 0.f);
  ((half4*)(out + (size_t)w * HID))[lane] = r;
}

// ---------------- GAT: per-node attention coefficients ---------------------------
__global__ __launch_bounds__(256) void gat_prep_kernel(
    const _Float16* __restrict__ hlin, const float* __restrict__ a_src,
    const float* __restrict__ a_dst, float* __restrict__ asad) {
  int w = (int)((blockIdx.x * blockDim.x + threadIdx.x) >> 6);
  int lane = threadIdx.x & 63;
  if (w >= N_NODES) return;
  half4 h = ((const half4*)(hlin + (size_t)w * HID))[lane];
  float4 s4 = ((const float4*)a_src)[lane];
  float4 d4 = ((const float4*)a_dst)[lane];
  float hx = h[0], hy = h[1], hz = h[2], hw = h[3];
  float ps = hx * s4.x + hy * s4.y + hz * s4.z + hw * s4.w;
  float pd = hx * d4.x + hy * d4.y + hz * d4.z + hw * d4.w;
  for (int o = 1; o < 8; o <<= 1) { ps += __shfl_xor(ps, o, 64); pd += __shfl_xor(pd, o, 64); }
  if ((lane & 7) == 0) {
    int hh = lane >> 3;
    asad[(size_t)w * 16 + hh] = ps;
    asad[(size_t)w * 16 + 8 + hh] = pd;
  }
}

// ---------------- per-head global max of a_src projections -----------------------
__global__ __launch_bounds__(256) void gmax_kernel(const float* __restrict__ asad,
                                                   unsigned* __restrict__ gmax) {
  int t = threadIdx.x;
  int h = t & 7;
  float m = -1e30f;
  for (int n = blockIdx.x * 32 + (t >> 3); n < N_NODES; n += gridDim.x * 32)
    m = fmaxf(m, asad[(size_t)n * 16 + h]);
  m = fmaxf(m, __shfl_xor(m, 8, 64));
  m = fmaxf(m, __shfl_xor(m, 16, 64));
  m = fmaxf(m, __shfl_xor(m, 32, 64));
  if ((t & 63) < 8) atomicMax(&gmax[h], f2ord(m));
}

static __device__ __forceinline__ float lrelu(float e) {
  return e > 0.f ? e : 0.2f * e;
}

// ---------------- GAT aggregation + LayerNorm + weighted accumulate --------------
__global__ __launch_bounds__(256) void gat_agg_kernel(
    const _Float16* __restrict__ hlin, const int* __restrict__ deg,
    const int* __restrict__ csr_src, const float* __restrict__ asad,
    const unsigned* __restrict__ gmax, const float* __restrict__ bias,
    const float* __restrict__ lng, const float* __restrict__ lnb,
    const float* __restrict__ wsel, int kk, float* __restrict__ dout) {
  int w = (int)((blockIdx.x * blockDim.x + threadIdx.x) >> 6);
  int lane = threadIdx.x & 63;
  if (w >= N_NODES) return;
  int head = lane >> 3;
  int e7 = lane & 7;
  int gsel = lane >> 4;
  float ad_d = asad[(size_t)w * 16 + 8 + head];
  float m = lrelu(ord2f(gmax[head]) + ad_d);
  float e_self = lrelu(asad[(size_t)w * 16 + head] + ad_d);
  float ad_e = __shfl(ad_d, e7 << 3, 64);
  float m_e = __shfl(m, e7 << 3, 64);
  int dg = deg[w];
  if (dg > DEGMAX) dg = DEGMAX;
  const int* sp = csr_src + (size_t)w * DEGMAX;
  float lA = __expf(e_self - m), lB = 0.f, lC = 0.f, lD = 0.f;
  half4 hv = ((const half4*)(hlin + (size_t)w * HID))[lane];
  float A0 = (float)hv[0] * lA, A1 = (float)hv[1] * lA,
        A2 = (float)hv[2] * lA, A3 = (float)hv[3] * lA;
  float B0 = 0.f, B1 = 0.f, B2 = 0.f, B3 = 0.f;
  float C0 = 0.f, C1 = 0.f, C2 = 0.f, C3 = 0.f;
  float D0 = 0.f, D1 = 0.f, D2 = 0.f, D3 = 0.f;
  int ng = (dg + 3) >> 2;
  int4 iv;
  if (ng) iv = *(const int4*)sp;
  for (int gi = 0; gi < ng; ++gi) {
    int s4 = gi << 2;
    int rem = dg - s4;
    bool tail = rem < 4;
    if (tail) {
      if (rem < 2) iv.y = iv.x;
      if (rem < 3) iv.z = iv.x;
      iv.w = iv.x;
    }
    int nsel = gsel == 0 ? iv.x : gsel == 1 ? iv.y : gsel == 2 ? iv.z : iv.w;
    float av = asad[(size_t)nsel * 16 + e7];
    half4 v0 = ((const half4*)(hlin + (size_t)iv.x * HID))[lane];
    half4 v1 = ((const half4*)(hlin + (size_t)iv.y * HID))[lane];
    half4 v2 = ((const half4*)(hlin + (size_t)iv.z * HID))[lane];
    half4 v3 = ((const half4*)(hlin + (size_t)iv.w * HID))[lane];
    int4 nx = iv;
    if (gi + 1 < ng) nx = *(const int4*)(sp + s4 + 4);
    float ve = __expf(lrelu(av + ad_e) - m_e);
    float w0 = __shfl(ve, head, 64);
    float w1 = __shfl(ve, 16 + head, 64);
    float w2 = __shfl(ve, 32 + head, 64);
    float w3 = __shfl(ve, 48 + head, 64);
    if (tail) {
      if (rem < 2) w1 = 0.f;
      if (rem < 3) w2 = 0.f;
      w3 = 0.f;
    }
    lA += w0; lB += w1; lC += w2; lD += w3;
    A0 += (float)v0[0] * w0; A1 += (float)v0[1] * w0; A2 += (float)v0[2] * w0; A3 += (float)v0[3] * w0;
    B0 += (float)v1[0] * w1; B1 += (float)v1[1] * w1; B2 += (float)v1[2] * w1; B3 += (float)v1[3] * w1;
    C0 += (float)v2[0] * w2; C1 += (float)v2[1] * w2; C2 += (float)v2[2] * w2; C3 += (float)v2[3] * w2;
    D0 += (float)v3[0] * w3; D1 += (float)v3[1] * w3; D2 += (float)v3[2] * w3; D3 += (float)v3[3] * w3;
    iv = nx;
  }
  float inv = 1.f / (lA + lB + lC + lD);
  float4 b = ((const float4*)bias)[lane];
  float vx = (A0 + B0 + C0 + D0) * inv + b.x;
  float vy = (A1 + B1 + C1 + D1) * inv + b.y;
  float vz = (A2 + B2 + C2 + D2) * inv + b.z;
  float vw = (A3 + B3 + C3 + D3) * inv + b.w;
  float ssum = vx + vy + vz + vw;
  for (int o = 1; o < 64; o <<= 1) ssum += __shfl_xor(ssum, o, 64);
  float mu = ssum * (1.f / HID);
  float dx = vx - mu, dy = vy - mu, dz = vz - mu, dw = vw - mu;
  float qq = dx * dx + dy * dy + dz * dz + dw * dw;
  for (int o = 1; o < 64; o <<= 1) qq += __shfl_xor(qq, o, 64);
  float rs = rsqrtf(qq * (1.f / HID) + 1e-5f);
  float4 g4 = ((const float4*)lng)[lane];
  float4 b4 = ((const float4*)lnb)[lane];
  float wk = wsel[(size_t)w * 4 + kk];
  float4 r;
  r.x = (dx * rs * g4.x + b4.x) * wk;
  r.y = (dy * rs * g4.y + b4.y) * wk;
  r.z = (dz * rs * g4.z + b4.z) * wk;
  r.w = (dw * rs * g4.w + b4.w) * wk;
  float4* dp = (float4*)(dout + (size_t)w * HID) + lane;
  if (kk == 0) {
    *dp = r;
  } else {
    float4 old = *dp;
    old.x += r.x; old.y += r.y; old.z += r.z; old.w += r.w;
    *dp = old;
  }
}

// ---------------- fusion weights: logits = t @ W2 + b2, softmax(K=4) --------------
__global__ __launch_bounds__(256) void fusw_kernel(
    const _Float16* __restrict__ t, const float* __restrict__ W2,
    const float* __restrict__ b2, float* __restrict__ wout) {
  int w = (int)((blockIdx.x * blockDim.x + threadIdx.x) >> 6);
  int lane = threadIdx.x & 63;
  if (w >= N_NODES) return;
  half4 t4h = ((const half4*)(t + (size_t)w * HID))[lane];
  float tx = t4h[0], ty = t4h[1], tz = t4h[2], tw = t4h[3];
  int c = lane * 4;
  float4 w0 = ((const float4*)W2)[c + 0];
  float4 w1 = ((const float4*)W2)[c + 1];
  float4 w2 = ((const float4*)W2)[c + 2];
  float4 w3 = ((const float4*)W2)[c + 3];
  float p0 = tx * w0.x + ty * w1.x + tz * w2.x + tw * w3.x;
  float p1 = tx * w0.y + ty * w1.y + tz * w2.y + tw * w3.y;
  float p2 = tx * w0.z + ty * w1.z + tz * w2.z + tw * w3.z;
  float p3 = tx * w0.w + ty * w1.w + tz * w2.w + tw * w3.w;
  for (int o = 1; o < 64; o <<= 1) {
    p0 += __shfl_xor(p0, o, 64); p1 += __shfl_xor(p1, o, 64);
    p2 += __shfl_xor(p2, o, 64); p3 += __shfl_xor(p3, o, 64);
  }
  if (lane == 0) {
    p0 += b2[0]; p1 += b2[1]; p2 += b2[2]; p3 += b2[3];
    float mx = fmaxf(fmaxf(p0, p1), fmaxf(p2, p3));
    float e0 = __expf(p0 - mx), e1 = __expf(p1 - mx), e2 = __expf(p2 - mx), e3 = __expf(p3 - mx);
    float inv = 1.f / (e0 + e1 + e2 + e3);
    float4 r; r.x = e0 * inv; r.y = e1 * inv; r.z = e2 * inv; r.w = e3 * inv;
    ((float4*)wout)[w] = r;
  }
}

extern "C" void kernel_launch(void* const* d_in, const int* in_sizes, int n_in,
                              void* d_out, int out_size, void* d_ws, size_t ws_size,
                              hipStream_t stream) {
  const float* x      = (const float*)d_in[0];
  const float* style  = (const float*)d_in[1];
  const float* stress = (const float*)d_in[2];
  const int* edges[4] = {(const int*)d_in[3], (const int*)d_in[4],
                         (const int*)d_in[5], (const int*)d_in[6]};
  const float* gW0 = (const float*)d_in[7];
  const float* gb0 = (const float*)d_in[8];
  const float* gW1 = (const float*)d_in[9];
  const float* gb1 = (const float*)d_in[10];
  const float* gW2 = (const float*)d_in[11];
  const float* gb2 = (const float*)d_in[12];
  const float* aW  = (const float*)d_in[13];
  const float* aas = (const float*)d_in[14];
  const float* aad = (const float*)d_in[15];
  const float* ab  = (const float*)d_in[16];
  const float* lg  = (const float*)d_in[17];
  const float* lb  = (const float*)d_in[18];
  const float* fW1 = (const float*)d_in[19];
  const float* fb1 = (const float*)d_in[20];
  const float* fW2 = (const float*)d_in[21];
  const float* fb2 = (const float*)d_in[22];
  float* out = (float*)d_out;
  (void)in_sizes; (void)n_in; (void)out_size;

  char* wsp = (char*)d_ws;
  size_t off = 0;
  auto alloc = [&](size_t bytes) -> void* {
    void* p = wsp + off;
    off += (bytes + 255) & ~(size_t)255;
    return p;
  };
  auto al = [](size_t b) { return (b + 255) & ~(size_t)255; };

  const size_t sz_hact = (size_t)N_NODES * HID * 2;
  const size_t sz_xh   = (size_t)N_NODES * IN_DIM * 2;
  const size_t sz_csr  = (size_t)N_NODES * DEGMAX * 4;
  const size_t sz_hlin0 = (size_t)4 * N_NODES * HID * 2;  // 102.4 MB

  const size_t fixed = al(sz_hact) * 2 + al(sz_xh) + al((size_t)WT_TOT * 2) +
                       al((size_t)N_NODES * 16) + al((size_t)N_NODES * 4) * 2 +
                       al((size_t)N_NODES * 64) + al(256);
  const size_t need_hoist = fixed + al(sz_csr) + al(sz_hlin0);
  const bool hoist = ws_size >= need_hoist;

  _Float16* h_act = (_Float16*)alloc(sz_hact);
  _Float16* h_lin = (_Float16*)alloc(sz_hact);
  _Float16* x_h   = (_Float16*)alloc(sz_xh);
  _Float16* wtall = (_Float16*)alloc((size_t)WT_TOT * 2);
  float* wsel = (float*)alloc((size_t)N_NODES * 16);
  float* dinv = (float*)alloc((size_t)N_NODES * 4);
  int* cur = (int*)alloc((size_t)N_NODES * 4);
  float* asad = (float*)alloc((size_t)N_NODES * 64);
  unsigned* gmax = (unsigned*)alloc(256);
  _Float16* ctx_h;
  int* csr_src;
  _Float16* h_lin0 = nullptr;
  if (hoist) {
    csr_src = (int*)alloc(sz_csr);
    char* region = (char*)alloc(sz_hlin0);  // ctx_h lives here until fusion GEMM done
    ctx_h = (_Float16*)region;
    h_lin0 = (_Float16*)region;
  } else {
    char* shared_region = (char*)alloc(sz_xh);  // 51.2 MB: ctx then csr
    ctx_h = (_Float16*)shared_region;
    csr_src = (int*)shared_region;
  }

  dim3 blk(256);
  const int nodeWaveBlocks = N_NODES / 4;
  const int nBlocksN = (N_NODES + 255) / 256;
  const int nBlocksE = (NEDGE + 255) / 256;
  const int gemmBlocks = (N_NODES + 127) / 128;  // 391

  // ---- one-time conversions ----
  conv_f2h_kernel<<<(N_NODES * IN_DIM / 4 + 255) / 256, blk, 0, stream>>>(x, x_h, N_NODES * IN_DIM / 4);
  conv_ctx_kernel<<<(N_NODES * 128 + 255) / 256, blk, 0, stream>>>(style, stress, ctx_h);
  wconv_all_kernel<<<(WT_TOT + 255) / 256, blk, 0, stream>>>(fW1, gW0, gW1, gW2, aW, wtall);

  // ---- fusion gate ----
  gemm_f16_kernel<512><<<gemmBlocks, blk, 0, stream>>>(ctx_h, wtall + WT_FUS, fb1, h_lin,
                                                       N_NODES, 1, nullptr, 0, 0);
  fusw_kernel<<<nodeWaveBlocks, blk, 0, stream>>>(h_lin, fW2, fb2, wsel);

  // ---- hoisted GCN0 linear: x @ W0_k for all 4 topologies in one dispatch ----
  if (hoist) {
    gemm_f16_kernel<512><<<dim3(gemmBlocks, 4), blk, 0, stream>>>(
        x_h, wtall + WT_G0, nullptr, h_lin0, N_NODES, 0, nullptr,
        131072, N_NODES * HID);
  }

  for (int k = 0; k < TOPO; ++k) {
    const int* srcp = edges[k];
    const int* dstp = edges[k] + NEDGE;
    zero_int_kernel<<<nBlocksN, blk, 0, stream>>>(cur, N_NODES, gmax);
    fill_kernel<<<nBlocksE, blk, 0, stream>>>(srcp, dstp, cur, csr_src, NEDGE);
    dinv_kernel<<<nBlocksN, blk, 0, stream>>>(cur, dinv, N_NODES);

    // GCN0 (512 -> 256)
    if (hoist) {
      gcn_agg_kernel<0><<<nodeWaveBlocks, blk, 0, stream>>>(
          h_lin0 + (size_t)k * N_NODES * HID, cur, csr_src, dinv,
          gb0 + (size_t)k * HID, h_act);
    } else {
      gemm_f16_kernel<512><<<gemmBlocks, blk, 0, stream>>>(
          x_h, wtall + WT_G0 + (size_t)k * 131072, nullptr, h_lin, N_NODES, 0, dinv, 0, 0);
      gcn_agg_kernel<1><<<nodeWaveBlocks, blk, 0, stream>>>(h_lin, cur, csr_src, dinv,
                                                            gb0 + (size_t)k * HID, h_act);
    }
    // GCN1
    gemm_f16_kernel<256><<<gemmBlocks, blk, 0, stream>>>(
        h_act, wtall + WT_G1 + (size_t)k * 65536, nullptr, h_lin, N_NODES, 0, dinv, 0, 0);
    gcn_agg_kernel<1><<<nodeWaveBlocks, blk, 0, stream>>>(h_lin, cur, csr_src, dinv,
                                                          gb1 + (size_t)k * HID, h_act);
    // GCN2
    gemm_f16_kernel<256><<<gemmBlocks, blk, 0, stream>>>(
        h_act, wtall + WT_G2 + (size_t)k * 65536, nullptr, h_lin, N_NODES, 0, dinv, 0, 0);
    gcn_agg_kernel<1><<<nodeWaveBlocks, blk, 0, stream>>>(h_lin, cur, csr_src, dinv,
                                                          gb2 + (size_t)k * HID, h_act);
    // GAT (unscaled linear output)
    gemm_f16_kernel<256><<<gemmBlocks, blk, 0, stream>>>(
        h_act, wtall + WT_AW + (size_t)k * 65536, nullptr, h_lin, N_NODES, 0, nullptr, 0, 0);
    gat_prep_kernel<<<nodeWaveBlocks, blk, 0, stream>>>(h_lin, aas + (size_t)k * HID,
                                                        aad + (size_t)k * HID, asad);
    gmax_kernel<<<64, blk, 0, stream>>>(asad, gmax);
    gat_agg_kernel<<<nodeWaveBlocks, blk, 0, stream>>>(h_lin, cur, csr_src, asad, gmax,
                                                       ab + (size_t)k * HID,
                                                       lg + (size_t)k * HID,
                                                       lb + (size_t)k * HID,
                                                       wsel, k, out);
  }
}